// Round 5
// baseline (86977.045 us; speedup 1.0000x reference)
//
#include <hip/hip_runtime.h>
#include <cstdint>

// RoleConditionedLSTMDecoder on MI355X (gfx950) — R5.
// R4 (27.2 ms) + (1) S3 fused into S2 via last-block-per-bm atomic (split-K-style
// serialization: fence + atomicAdd, no spinning), (2) c0/c1 transposed [cg][row]
// so epilogue cell-state I/O is f32x4 instead of 16 scalar 4B ops.
// Gate-permuted weight rows: perm j = tile*128 + half*64 + gate*16 + c16
// (h-col = tile*32 + half*16 + c16) -> lane's 4 col-frags = i,f,g,o of one (row,h-col).

#define DEVI __device__ __forceinline__

typedef __bf16 bf16x8 __attribute__((ext_vector_type(8)));
typedef float  f32x4  __attribute__((ext_vector_type(4)));
typedef float  f32x2  __attribute__((ext_vector_type(2)));
typedef unsigned short u16x4 __attribute__((ext_vector_type(4)));

static constexpr int NROWS = 22528;   // B*P
static constexpr int T_STEPS = 100;
static constexpr int NBM = 176;       // 22528/128 row-tiles

DEVI unsigned short f2bf(float f) {
  unsigned u = __float_as_uint(f);
  u = u + 0x7FFFu + ((u >> 16) & 1u);   // RNE
  return (unsigned short)(u >> 16);
}
DEVI float bf2f(unsigned short h) { return __uint_as_float(((unsigned)h) << 16); }

DEVI float fast_sigmoid(float x) {
  float e = __builtin_amdgcn_exp2f(-1.442695041f * x);
  return __builtin_amdgcn_rcpf(1.0f + e);
}
DEVI float fast_tanh(float x) {
  float e = __builtin_amdgcn_exp2f(2.885390082f * x);   // e^(2x)
  return 1.0f - 2.0f * __builtin_amdgcn_rcpf(e + 1.0f);
}

DEVI void async_copy16(const void* g, void* l) {
  __builtin_amdgcn_global_load_lds(
      (const __attribute__((address_space(1))) void*)g,
      (__attribute__((address_space(3))) void*)l, 16, 0, 0);
}

// ---------------- 128x128 GEMM core (BK=64, 256 thr, 4 waves 2x2) — proven ----------------
template <int KITERS, int KSWITCH>
DEVI void gemm_core(const unsigned short* __restrict__ A1, int lda1,
                    const unsigned short* __restrict__ A2, int lda2,
                    const unsigned short* __restrict__ B1, int ldb1,
                    const unsigned short* __restrict__ B2, int ldb2,
                    unsigned short* lds, f32x4 acc[4][4], int tid) {
  const int lane = tid & 63, wid = tid >> 6;
  const int wm = wid & 1, wn = wid >> 1;
  const int c16 = lane & 15, q = lane >> 4;
#pragma unroll
  for (int i = 0; i < 4; ++i)
#pragma unroll
    for (int j = 0; j < 4; ++j) acc[i][j] = f32x4{0.f, 0.f, 0.f, 0.f};
  for (int kt = 0; kt < KITERS; ++kt) {
    const bool sec = (kt >= KSWITCH);
    const unsigned short* Ab = sec ? A2 : A1;
    const unsigned short* Bb = sec ? B2 : B1;
    const int lda = sec ? lda2 : lda1;
    const int ldb = sec ? ldb2 : ldb1;
    const int kk = (sec ? (kt - KSWITCH) : kt) * 64;
    __syncthreads();                       // prior reads done before overwrite
#pragma unroll
    for (int rd = 0; rd < 4; ++rd) {
      int p = rd * 256 + tid;
      int row = p >> 3, u = p & 7, ch = u ^ (row & 7);
      async_copy16(Ab + row * lda + kk + ch * 8, lds + p * 8);
      async_copy16(Bb + row * ldb + kk + ch * 8, lds + 8192 + p * 8);
    }
    __syncthreads();
#pragma unroll
    for (int s = 0; s < 2; ++s) {
      bf16x8 a[4], b[4];
#pragma unroll
      for (int mf = 0; mf < 4; ++mf) {
        int row = wm * 64 + mf * 16 + c16;
        int slot = row * 8 + ((s * 4 + q) ^ (row & 7));
        a[mf] = *(const bf16x8*)(lds + slot * 8);
      }
#pragma unroll
      for (int nf = 0; nf < 4; ++nf) {
        int row = wn * 64 + nf * 16 + c16;
        int slot = row * 8 + ((s * 4 + q) ^ (row & 7));
        b[nf] = *(const bf16x8*)(lds + 8192 + slot * 8);
      }
#pragma unroll
      for (int mf = 0; mf < 4; ++mf)
#pragma unroll
        for (int nf = 0; nf < 4; ++nf)
          acc[mf][nf] = __builtin_amdgcn_mfma_f32_16x16x32_bf16(a[mf], b[nf], acc[mf][nf], 0, 0, 0);
    }
  }
}

// ---------------- prep ----------------
DEVI int orig_row(int j) {  // permuted gate-col -> original row of [4H x K] weight
  int tile = j >> 7, rem = j & 127;
  int half = rem >> 6, g = (rem >> 4) & 3, cc = rem & 15;
  return g * 512 + (tile * 32 + half * 16 + cc);
}

__global__ void k_prep_w(const float* __restrict__ Whh0, const float* __restrict__ Wih1,
                         const float* __restrict__ Whh1, const float* __restrict__ Wih0,
                         const float* __restrict__ Wfc1, const float* __restrict__ b0,
                         const float* __restrict__ b1,
                         unsigned short* __restrict__ W0p, unsigned short* __restrict__ Wc1p,
                         unsigned short* __restrict__ Wsp, unsigned short* __restrict__ Wfc1b,
                         float* __restrict__ Wposx, float* __restrict__ Wposy,
                         float* __restrict__ b0p4, float* __restrict__ b1p4) {
  int j = blockIdx.x;       // 0..2047
  int k = threadIdx.x;      // 0..511
  int o = orig_row(j);
  W0p[j * 512 + k]         = f2bf(Whh0[o * 512 + k]);
  Wc1p[j * 1024 + k]       = f2bf(Wih1[o * 512 + k]);
  Wc1p[j * 1024 + 512 + k] = f2bf(Whh1[o * 512 + k]);
  if (k < 384) Wsp[j * 384 + k] = (k < 322) ? f2bf(Wih0[o * 324 + 2 + k]) : (unsigned short)0;
  if (k == 0) {
    int g = (j >> 4) & 3;
    int cg = (j >> 7) * 32 + ((j >> 6) & 1) * 16 + (j & 15);
    Wposx[cg * 4 + g] = Wih0[o * 324 + 0];
    Wposy[cg * 4 + g] = Wih0[o * 324 + 1];
    b0p4[cg * 4 + g] = b0[o];
    b1p4[cg * 4 + g] = b1[o];
  }
  if (j < 256) Wfc1b[j * 512 + k] = f2bf(Wfc1[j * 512 + k]);
}

__global__ void k_init_xs(const float* __restrict__ ball, const float* __restrict__ ctx,
                          const int* __restrict__ roles, const float* __restrict__ role_table,
                          unsigned short* __restrict__ Xs) {
  int n = blockIdx.x, col = threadIdx.x;  // 22528 x 384
  int b = n / 22;
  float v;
  if (col < 2)        v = ball[b * 2 + col];
  else if (col < 258) v = ctx[(size_t)n * 256 + col - 2];
  else if (col < 322) v = role_table[roles[n] * 64 + col - 258];
  else                v = 0.f;
  Xs[(size_t)n * 384 + col] = f2bf(v);
}

__global__ void k_init_state(const float* __restrict__ pos0, const float* __restrict__ Winit,
                             const float* __restrict__ binit, unsigned short* __restrict__ Hcat,
                             float* __restrict__ c0, float* __restrict__ c1,
                             float* __restrict__ posb, int* __restrict__ counters) {
  int idx = blockIdx.x * 256 + threadIdx.x;     // N*512
  if (idx >= NROWS * 512) return;
  if (idx < T_STEPS * NBM) counters[idx] = 0;
  int n = idx >> 9, c = idx & 511;
  float px = pos0[n * 2 + 0], py = pos0[n * 2 + 1];
  float h0 = binit[c] + Winit[c * 2 + 0] * px + Winit[c * 2 + 1] * py;
  Hcat[(size_t)n * 1024 + c] = f2bf(h0);
  Hcat[(size_t)n * 1024 + 512 + c] = 0;   // h1 = 0
  c0[idx] = 0.f;                          // layouts differ but both fully zeroed
  c1[idx] = 0.f;
  if (c < 2) posb[n * 2 + c] = pos0[n * 2 + c];
}

// static_proj packed: SP2[row*512+cg] = ushort4{i,f,g,o} + b0 — SP path only
__global__ __launch_bounds__(256) void k_static(const unsigned short* __restrict__ Xs,
                                                const unsigned short* __restrict__ Wsp,
                                                const float* __restrict__ b0p4,
                                                unsigned short* __restrict__ SP2) {
  __shared__ __align__(16) unsigned short lds[16384];
  int tid = threadIdx.x, bn = blockIdx.x, bm = blockIdx.y;
  f32x4 acc[4][4];
  const unsigned short* Ab = Xs + (size_t)bm * 128 * 384;
  const unsigned short* Bb = Wsp + (size_t)bn * 128 * 384;
  gemm_core<6, 6>(Ab, 384, Ab, 384, Bb, 384, Bb, 384, lds, acc, tid);
  int lane = tid & 63, wid = tid >> 6, wm = wid & 1, wn = wid >> 1;
  int c16 = lane & 15, q = lane >> 4;
  int cg = bn * 32 + wn * 16 + c16;
  f32x4 bb = *(const f32x4*)&b0p4[cg * 4];
#pragma unroll
  for (int mf = 0; mf < 4; ++mf) {
    int row0 = bm * 128 + wm * 64 + mf * 16 + q * 4;
#pragma unroll
    for (int r = 0; r < 4; ++r) {
      u16x4 v;
      v.x = f2bf(acc[mf][0][r] + bb.x);
      v.y = f2bf(acc[mf][1][r] + bb.y);
      v.z = f2bf(acc[mf][2][r] + bb.z);
      v.w = f2bf(acc[mf][3][r] + bb.w);
      ((u16x4*)SP2)[(size_t)(row0 + r) * 512 + cg] = v;
    }
  }
}

// ---------------- per-step ----------------
// S1: gates0 = h0_prev @ W0p^T (+ static) + pos@Wpos^T ; cell0 -> h0 into nxt[:,0:512]
// c0 layout: [cg][row] (transposed) -> f32x4 per (mf).
template <bool USE_SP>
__global__ __launch_bounds__(256) void k_s1(const unsigned short* __restrict__ cur,
                                            const unsigned short* __restrict__ Xs,
                                            const unsigned short* __restrict__ W0p,
                                            const unsigned short* __restrict__ Wsp,
                                            const unsigned short* __restrict__ SP2,
                                            const float* __restrict__ b0p4,
                                            const float* __restrict__ Wposx,
                                            const float* __restrict__ Wposy,
                                            const float* __restrict__ posb,
                                            float* __restrict__ c0,
                                            unsigned short* __restrict__ nxt) {
  __shared__ __align__(16) unsigned short lds[16384];
  int tid = threadIdx.x, bn = blockIdx.x, bm = blockIdx.y;
  f32x4 acc[4][4];
  const unsigned short* A1 = cur + (size_t)bm * 128 * 1024;
  const unsigned short* B1 = W0p + (size_t)bn * 128 * 512;
  if constexpr (USE_SP) {
    gemm_core<8, 8>(A1, 1024, A1, 1024, B1, 512, B1, 512, lds, acc, tid);
  } else {
    const unsigned short* A2 = Xs + (size_t)bm * 128 * 384;
    const unsigned short* B2 = Wsp + (size_t)bn * 128 * 384;
    gemm_core<14, 8>(A1, 1024, A2, 384, B1, 512, B2, 384, lds, acc, tid);
  }
  int lane = tid & 63, wid = tid >> 6, wm = wid & 1, wn = wid >> 1;
  int c16 = lane & 15, q = lane >> 4;
  int cg = bn * 32 + wn * 16 + c16;
  f32x4 wpx = *(const f32x4*)&Wposx[cg * 4];
  f32x4 wpy = *(const f32x4*)&Wposy[cg * 4];
  f32x4 sb = f32x4{0.f, 0.f, 0.f, 0.f};
  if constexpr (!USE_SP) sb = *(const f32x4*)&b0p4[cg * 4];
#pragma unroll
  for (int mf = 0; mf < 4; ++mf) {
    int row0 = bm * 128 + wm * 64 + mf * 16 + q * 4;
    f32x4 cold = *(const f32x4*)&c0[(size_t)cg * NROWS + row0];
    f32x4 cnew;
#pragma unroll
    for (int r = 0; r < 4; ++r) {
      size_t row = row0 + r;
      f32x2 pv = *(const f32x2*)&posb[row * 2];
      float s0 = sb.x, s1 = sb.y, s2 = sb.z, s3 = sb.w;
      if constexpr (USE_SP) {
        u16x4 sp = ((const u16x4*)SP2)[row * 512 + cg];
        s0 = bf2f(sp.x); s1 = bf2f(sp.y); s2 = bf2f(sp.z); s3 = bf2f(sp.w);
      }
      float gi = acc[mf][0][r] + s0 + pv.x * wpx.x + pv.y * wpy.x;
      float gf = acc[mf][1][r] + s1 + pv.x * wpx.y + pv.y * wpy.y;
      float gg = acc[mf][2][r] + s2 + pv.x * wpx.z + pv.y * wpy.z;
      float go = acc[mf][3][r] + s3 + pv.x * wpx.w + pv.y * wpy.w;
      float cn = fast_sigmoid(gf) * cold[r] + fast_sigmoid(gi) * fast_tanh(gg);
      cnew[r] = cn;
      nxt[row * 1024 + cg] = f2bf(fast_sigmoid(go) * fast_tanh(cn));
    }
    *(f32x4*)&c0[(size_t)cg * NROWS + row0] = cnew;
  }
}

// S2 fused: gates1 GEMM + cell1 -> h1; then the LAST block per bm (fence+atomic)
// runs fc1+relu+fc2 for its 128 rows (2 row-halves x 2 col-passes) and writes out/posb.
__global__ __launch_bounds__(256) void k_s2f(const unsigned short* __restrict__ nxt_in,
                                             const unsigned short* __restrict__ cur,
                                             const unsigned short* __restrict__ Wc1p,
                                             const float* __restrict__ b1p4,
                                             float* __restrict__ c1,
                                             unsigned short* __restrict__ nxt_out,
                                             const unsigned short* __restrict__ Wfc1b,
                                             const float* __restrict__ bfc1,
                                             const float* __restrict__ Wfc2,
                                             const float* __restrict__ bfc2,
                                             float* __restrict__ out,
                                             float* __restrict__ posb,
                                             int* __restrict__ cnt, int t) {
  __shared__ __align__(16) unsigned short lds[16896];   // 33 KB: gemm 32 KB + red 1 KB
  __shared__ int lastflag;
  int tid = threadIdx.x, bn = blockIdx.x, bm = blockIdx.y;
  f32x4 acc[4][4];
  const unsigned short* A1 = nxt_in + (size_t)bm * 128 * 1024;        // h0_t
  const unsigned short* A2 = cur + (size_t)bm * 128 * 1024 + 512;     // h1_{t-1}
  const unsigned short* B1 = Wc1p + (size_t)bn * 128 * 1024;
  gemm_core<16, 8>(A1, 1024, A2, 1024, B1, 1024, B1 + 512, 1024, lds, acc, tid);
  int lane = tid & 63, wid = tid >> 6, wm = wid & 1, wn = wid >> 1;
  int c16 = lane & 15, q = lane >> 4;
  int cg = bn * 32 + wn * 16 + c16;
  f32x4 bv = *(const f32x4*)&b1p4[cg * 4];
#pragma unroll
  for (int mf = 0; mf < 4; ++mf) {
    int row0 = bm * 128 + wm * 64 + mf * 16 + q * 4;
    f32x4 cold = *(const f32x4*)&c1[(size_t)cg * NROWS + row0];
    f32x4 cnew;
#pragma unroll
    for (int r = 0; r < 4; ++r) {
      size_t row = row0 + r;
      float gi = acc[mf][0][r] + bv.x;
      float gf = acc[mf][1][r] + bv.y;
      float gg = acc[mf][2][r] + bv.z;
      float go = acc[mf][3][r] + bv.w;
      float cn = fast_sigmoid(gf) * cold[r] + fast_sigmoid(gi) * fast_tanh(gg);
      cnew[r] = cn;
      nxt_out[row * 1024 + 512 + cg] = f2bf(fast_sigmoid(go) * fast_tanh(cn));
    }
    *(f32x4*)&c1[(size_t)cg * NROWS + row0] = cnew;
  }

  // ---- last-block-per-bm serialization (no spin) ----
  __threadfence();                                   // release h1 stores device-wide
  __syncthreads();
  if (tid == 0) lastflag = (atomicAdd(&cnt[bm], 1) == 15);
  __syncthreads();
  if (!lastflag) return;
  __threadfence();                                   // acquire siblings' h1

  // fused fc: rows bm*128..+127, Hrow = nxt_out[:,512:1024]
  float* red = (float*)(lds + 16384);                // 64*4 floats
#pragma unroll 1
  for (int half = 0; half < 2; ++half) {
    const unsigned short* Arow = nxt_out + (size_t)(bm * 128 + half * 64) * 1024 + 512;
    float part[2][2][4];
#pragma unroll
    for (int d = 0; d < 2; ++d)
#pragma unroll
      for (int mf = 0; mf < 2; ++mf)
#pragma unroll
        for (int r = 0; r < 4; ++r) part[d][mf][r] = 0.f;
#pragma unroll 1
    for (int cp = 0; cp < 2; ++cp) {
      f32x4 acc2[2][4];
#pragma unroll
      for (int i = 0; i < 2; ++i)
#pragma unroll
        for (int j = 0; j < 4; ++j) acc2[i][j] = f32x4{0.f, 0.f, 0.f, 0.f};
      for (int kt = 0; kt < 8; ++kt) {
        int k0 = kt * 64;
        __syncthreads();
#pragma unroll
        for (int rd = 0; rd < 2; ++rd) {             // A: 64 rows x 8 chunks
          int p = rd * 256 + tid;
          int row = p >> 3, u = p & 7, ch = u ^ (row & 7);
          async_copy16(Arow + (size_t)row * 1024 + k0 + ch * 8, lds + p * 8);
        }
#pragma unroll
        for (int rd = 0; rd < 4; ++rd) {             // B: 128 fc1-cols x 8 chunks
          int p = rd * 256 + tid;
          int row = p >> 3, u = p & 7, ch = u ^ (row & 7);
          async_copy16(Wfc1b + (size_t)(cp * 128 + row) * 512 + k0 + ch * 8,
                       lds + 4096 + p * 8);
        }
        __syncthreads();
#pragma unroll
        for (int s = 0; s < 2; ++s) {
          bf16x8 a[2], b[4];
#pragma unroll
          for (int mf = 0; mf < 2; ++mf) {
            int row = wm * 32 + mf * 16 + c16;
            int slot = row * 8 + ((s * 4 + q) ^ (row & 7));
            a[mf] = *(const bf16x8*)(lds + slot * 8);
          }
#pragma unroll
          for (int nf = 0; nf < 4; ++nf) {
            int row = wn * 64 + nf * 16 + c16;
            int slot = row * 8 + ((s * 4 + q) ^ (row & 7));
            b[nf] = *(const bf16x8*)(lds + 4096 + slot * 8);
          }
#pragma unroll
          for (int mf = 0; mf < 2; ++mf)
#pragma unroll
            for (int nf = 0; nf < 4; ++nf)
              acc2[mf][nf] = __builtin_amdgcn_mfma_f32_16x16x32_bf16(a[mf], b[nf], acc2[mf][nf], 0, 0, 0);
        }
      }
#pragma unroll
      for (int nf = 0; nf < 4; ++nf) {
        int colg = cp * 128 + wn * 64 + nf * 16 + c16;
        float bvv = bfc1[colg], w0 = Wfc2[colg], w1 = Wfc2[256 + colg];
#pragma unroll
        for (int mf = 0; mf < 2; ++mf)
#pragma unroll
          for (int r = 0; r < 4; ++r) {
            float v = acc2[mf][nf][r] + bvv;
            v = v > 0.f ? v : 0.f;
            part[0][mf][r] += v * w0;
            part[1][mf][r] += v * w1;
          }
      }
    }
#pragma unroll
    for (int st = 1; st < 16; st <<= 1)
#pragma unroll
      for (int d = 0; d < 2; ++d)
#pragma unroll
        for (int mf = 0; mf < 2; ++mf)
#pragma unroll
          for (int r = 0; r < 4; ++r)
            part[d][mf][r] += __shfl_xor(part[d][mf][r], st, 64);
    if (c16 == 0) {
#pragma unroll
      for (int mf = 0; mf < 2; ++mf)
#pragma unroll
        for (int r = 0; r < 4; ++r) {
          int rl = wm * 32 + mf * 16 + q * 4 + r;
          red[rl * 4 + wn * 2 + 0] = part[0][mf][r];
          red[rl * 4 + wn * 2 + 1] = part[1][mf][r];
        }
    }
    __syncthreads();
    if (tid < 128) {
      int rl = tid >> 1, d = tid & 1;
      float s = red[rl * 4 + d] + red[rl * 4 + 2 + d] + bfc2[d];
      int rg = bm * 128 + half * 64 + rl;
      out[((size_t)rg * T_STEPS + t) * 2 + d] = s;
      posb[rg * 2 + d] = s;
    }
  }
}

// ---------------- launch ----------------
extern "C" void kernel_launch(void* const* d_in, const int* in_sizes, int n_in,
                              void* d_out, int out_size, void* d_ws, size_t ws_size,
                              hipStream_t stream) {
  (void)in_sizes; (void)n_in; (void)out_size;
  const float* ctx   = (const float*)d_in[0];
  const float* pos0  = (const float*)d_in[1];
  const float* ball  = (const float*)d_in[2];
  const int*   roles = (const int*)d_in[3];
  const float* role_table = (const float*)d_in[5];
  const float* Wih0 = (const float*)d_in[6];
  const float* Whh0 = (const float*)d_in[7];
  const float* b0   = (const float*)d_in[8];
  const float* Wih1 = (const float*)d_in[9];
  const float* Whh1 = (const float*)d_in[10];
  const float* b1   = (const float*)d_in[11];
  const float* Wfc1 = (const float*)d_in[12];
  const float* bfc1 = (const float*)d_in[13];
  const float* Wfc2 = (const float*)d_in[14];
  const float* bfc2 = (const float*)d_in[15];
  const float* Winit = (const float*)d_in[16];
  const float* binit = (const float*)d_in[17];
  float* out = (float*)d_out;

  char* w = (char*)d_ws;
  size_t used = 0;
  auto alloc = [&](size_t bytes) {
    char* p = w + used;
    used += (bytes + 255) & ~(size_t)255;
    return p;
  };
  unsigned short* W0p   = (unsigned short*)alloc((size_t)2048 * 512 * 2);
  unsigned short* Wc1p  = (unsigned short*)alloc((size_t)2048 * 1024 * 2);
  unsigned short* Wfc1b = (unsigned short*)alloc((size_t)256 * 512 * 2);
  float* Wposx = (float*)alloc(2048 * 4);
  float* Wposy = (float*)alloc(2048 * 4);
  float* b0p4  = (float*)alloc(2048 * 4);
  float* b1p4  = (float*)alloc(2048 * 4);
  float* posb  = (float*)alloc((size_t)NROWS * 2 * 4);
  int*   counters = (int*)alloc((size_t)T_STEPS * NBM * 4);
  unsigned short* Hc0 = (unsigned short*)alloc((size_t)NROWS * 1024 * 2);
  float* c0   = (float*)alloc((size_t)NROWS * 512 * 4);
  float* c1   = (float*)alloc((size_t)NROWS * 512 * 4);
  unsigned short* Hc1 = (unsigned short*)alloc((size_t)NROWS * 1024 * 2);

  const size_t SP_BYTES = (size_t)NROWS * 2048 * 2;           // 92.3 MB
  const bool use_sp = (ws_size >= used + SP_BYTES + (1u << 20));

  unsigned short *Xs, *Wsp, *SP2;
  if (use_sp) {
    SP2 = (unsigned short*)alloc(SP_BYTES);
    Xs  = Hc1;                                 // transient: dead before Hc1 is written
    Wsp = Hc1 + (size_t)NROWS * 384;
  } else {
    SP2 = Hc1;                                 // never dereferenced on lite path
    Xs  = (unsigned short*)alloc((size_t)NROWS * 384 * 2);
    Wsp = (unsigned short*)alloc((size_t)2048 * 384 * 2);
  }

  k_prep_w<<<2048, 512, 0, stream>>>(Whh0, Wih1, Whh1, Wih0, Wfc1, b0, b1,
                                     W0p, Wc1p, Wsp, Wfc1b, Wposx, Wposy, b0p4, b1p4);
  k_init_xs<<<NROWS, 384, 0, stream>>>(ball, ctx, roles, role_table, Xs);
  k_init_state<<<(NROWS * 512 + 255) / 256, 256, 0, stream>>>(pos0, Winit, binit, Hc0, c0, c1,
                                                              posb, counters);

  dim3 g1(16, NBM);
  if (use_sp) k_static<<<g1, 256, 0, stream>>>(Xs, Wsp, b0p4, SP2);

  for (int t = 0; t < T_STEPS; ++t) {
    unsigned short* cur = (t & 1) ? Hc1 : Hc0;
    unsigned short* nxt = (t & 1) ? Hc0 : Hc1;
    if (use_sp)
      k_s1<true><<<g1, 256, 0, stream>>>(cur, Xs, W0p, Wsp, SP2, b0p4, Wposx, Wposy, posb, c0, nxt);
    else
      k_s1<false><<<g1, 256, 0, stream>>>(cur, Xs, W0p, Wsp, SP2, b0p4, Wposx, Wposy, posb, c0, nxt);
    k_s2f<<<g1, 256, 0, stream>>>(nxt, cur, Wc1p, b1p4, c1, nxt,
                                  Wfc1b, bfc1, Wfc2, bfc2, out, posb,
                                  counters + t * NBM, t);
  }
}

// Round 6
// 27200.311 us; speedup vs baseline: 3.1976x; 3.1976x over previous
//
#include <hip/hip_runtime.h>
#include <cstdint>

// RoleConditionedLSTMDecoder on MI355X (gfx950) — R6.
// = R4 3-kernel structure (proven 27.2 ms) + R5's c0/c1 [cg][row] transpose
//   (verified bit-identical) + XCD-aware grid swizzle (all 16 bn-blocks of a
//   bm land on XCD bm&7 so the A-tile is L2-filled once, not ~8x).
// R5's fence+atomic fusion REMOVED: 2816 device-scope fences/dispatch poisoned
// the per-XCD L2s (795 us/dispatch, MfmaUtil 4.9%, 250 MB refetch).
// Gate-permuted weight rows: perm j = tile*128 + half*64 + gate*16 + c16
// (h-col = tile*32 + half*16 + c16) -> lane's 4 col-frags = i,f,g,o of one (row,h-col).

#define DEVI __device__ __forceinline__

typedef __bf16 bf16x8 __attribute__((ext_vector_type(8)));
typedef float  f32x4  __attribute__((ext_vector_type(4)));
typedef float  f32x2  __attribute__((ext_vector_type(2)));
typedef unsigned short u16x4 __attribute__((ext_vector_type(4)));

static constexpr int NROWS = 22528;   // B*P
static constexpr int T_STEPS = 100;
static constexpr int NBM = 176;       // 22528/128 row-tiles

DEVI unsigned short f2bf(float f) {
  unsigned u = __float_as_uint(f);
  u = u + 0x7FFFu + ((u >> 16) & 1u);   // RNE
  return (unsigned short)(u >> 16);
}
DEVI float bf2f(unsigned short h) { return __uint_as_float(((unsigned)h) << 16); }

DEVI float fast_sigmoid(float x) {
  float e = __builtin_amdgcn_exp2f(-1.442695041f * x);
  return __builtin_amdgcn_rcpf(1.0f + e);
}
DEVI float fast_tanh(float x) {
  float e = __builtin_amdgcn_exp2f(2.885390082f * x);   // e^(2x)
  return 1.0f - 2.0f * __builtin_amdgcn_rcpf(e + 1.0f);
}

DEVI void async_copy16(const void* g, void* l) {
  __builtin_amdgcn_global_load_lds(
      (const __attribute__((address_space(1))) void*)g,
      (__attribute__((address_space(3))) void*)l, 16, 0, 0);
}

// ---------------- 128x128 GEMM core (BK=64, 256 thr, 4 waves 2x2) — proven ----------------
template <int KITERS, int KSWITCH>
DEVI void gemm_core(const unsigned short* __restrict__ A1, int lda1,
                    const unsigned short* __restrict__ A2, int lda2,
                    const unsigned short* __restrict__ B1, int ldb1,
                    const unsigned short* __restrict__ B2, int ldb2,
                    unsigned short* lds, f32x4 acc[4][4], int tid) {
  const int lane = tid & 63, wid = tid >> 6;
  const int wm = wid & 1, wn = wid >> 1;
  const int c16 = lane & 15, q = lane >> 4;
#pragma unroll
  for (int i = 0; i < 4; ++i)
#pragma unroll
    for (int j = 0; j < 4; ++j) acc[i][j] = f32x4{0.f, 0.f, 0.f, 0.f};
  for (int kt = 0; kt < KITERS; ++kt) {
    const bool sec = (kt >= KSWITCH);
    const unsigned short* Ab = sec ? A2 : A1;
    const unsigned short* Bb = sec ? B2 : B1;
    const int lda = sec ? lda2 : lda1;
    const int ldb = sec ? ldb2 : ldb1;
    const int kk = (sec ? (kt - KSWITCH) : kt) * 64;
    __syncthreads();                       // prior reads done before overwrite
#pragma unroll
    for (int rd = 0; rd < 4; ++rd) {
      int p = rd * 256 + tid;
      int row = p >> 3, u = p & 7, ch = u ^ (row & 7);
      async_copy16(Ab + row * lda + kk + ch * 8, lds + p * 8);
      async_copy16(Bb + row * ldb + kk + ch * 8, lds + 8192 + p * 8);
    }
    __syncthreads();
#pragma unroll
    for (int s = 0; s < 2; ++s) {
      bf16x8 a[4], b[4];
#pragma unroll
      for (int mf = 0; mf < 4; ++mf) {
        int row = wm * 64 + mf * 16 + c16;
        int slot = row * 8 + ((s * 4 + q) ^ (row & 7));
        a[mf] = *(const bf16x8*)(lds + slot * 8);
      }
#pragma unroll
      for (int nf = 0; nf < 4; ++nf) {
        int row = wn * 64 + nf * 16 + c16;
        int slot = row * 8 + ((s * 4 + q) ^ (row & 7));
        b[nf] = *(const bf16x8*)(lds + 8192 + slot * 8);
      }
#pragma unroll
      for (int mf = 0; mf < 4; ++mf)
#pragma unroll
        for (int nf = 0; nf < 4; ++nf)
          acc[mf][nf] = __builtin_amdgcn_mfma_f32_16x16x32_bf16(a[mf], b[nf], acc[mf][nf], 0, 0, 0);
    }
  }
}

// ---------------- prep ----------------
DEVI int orig_row(int j) {  // permuted gate-col -> original row of [4H x K] weight
  int tile = j >> 7, rem = j & 127;
  int half = rem >> 6, g = (rem >> 4) & 3, cc = rem & 15;
  return g * 512 + (tile * 32 + half * 16 + cc);
}

__global__ void k_prep_w(const float* __restrict__ Whh0, const float* __restrict__ Wih1,
                         const float* __restrict__ Whh1, const float* __restrict__ Wih0,
                         const float* __restrict__ Wfc1, const float* __restrict__ b0,
                         const float* __restrict__ b1,
                         unsigned short* __restrict__ W0p, unsigned short* __restrict__ Wc1p,
                         unsigned short* __restrict__ Wsp, unsigned short* __restrict__ Wfc1b,
                         float* __restrict__ Wposx, float* __restrict__ Wposy,
                         float* __restrict__ b0p4, float* __restrict__ b1p4) {
  int j = blockIdx.x;       // 0..2047
  int k = threadIdx.x;      // 0..511
  int o = orig_row(j);
  W0p[j * 512 + k]         = f2bf(Whh0[o * 512 + k]);
  Wc1p[j * 1024 + k]       = f2bf(Wih1[o * 512 + k]);
  Wc1p[j * 1024 + 512 + k] = f2bf(Whh1[o * 512 + k]);
  if (k < 384) Wsp[j * 384 + k] = (k < 322) ? f2bf(Wih0[o * 324 + 2 + k]) : (unsigned short)0;
  if (k == 0) {
    int g = (j >> 4) & 3;
    int cg = (j >> 7) * 32 + ((j >> 6) & 1) * 16 + (j & 15);
    Wposx[cg * 4 + g] = Wih0[o * 324 + 0];
    Wposy[cg * 4 + g] = Wih0[o * 324 + 1];
    b0p4[cg * 4 + g] = b0[o];
    b1p4[cg * 4 + g] = b1[o];
  }
  if (j < 256) Wfc1b[j * 512 + k] = f2bf(Wfc1[j * 512 + k]);
}

__global__ void k_init_xs(const float* __restrict__ ball, const float* __restrict__ ctx,
                          const int* __restrict__ roles, const float* __restrict__ role_table,
                          unsigned short* __restrict__ Xs) {
  int n = blockIdx.x, col = threadIdx.x;  // 22528 x 384
  int b = n / 22;
  float v;
  if (col < 2)        v = ball[b * 2 + col];
  else if (col < 258) v = ctx[(size_t)n * 256 + col - 2];
  else if (col < 322) v = role_table[roles[n] * 64 + col - 258];
  else                v = 0.f;
  Xs[(size_t)n * 384 + col] = f2bf(v);
}

__global__ void k_init_state(const float* __restrict__ pos0, const float* __restrict__ Winit,
                             const float* __restrict__ binit, unsigned short* __restrict__ Hcat,
                             float* __restrict__ c0, float* __restrict__ c1,
                             float* __restrict__ posb) {
  int idx = blockIdx.x * 256 + threadIdx.x;     // N*512
  if (idx >= NROWS * 512) return;
  int n = idx >> 9, c = idx & 511;
  float px = pos0[n * 2 + 0], py = pos0[n * 2 + 1];
  float h0 = binit[c] + Winit[c * 2 + 0] * px + Winit[c * 2 + 1] * py;
  Hcat[(size_t)n * 1024 + c] = f2bf(h0);
  Hcat[(size_t)n * 1024 + 512 + c] = 0;   // h1 = 0
  c0[idx] = 0.f;                          // [cg][row] layout; fully zeroed either way
  c1[idx] = 0.f;
  if (c < 2) posb[n * 2 + c] = pos0[n * 2 + c];
}

// static_proj packed: SP2[row*512+cg] = ushort4{i,f,g,o} + b0 — SP path only
__global__ __launch_bounds__(256) void k_static(const unsigned short* __restrict__ Xs,
                                                const unsigned short* __restrict__ Wsp,
                                                const float* __restrict__ b0p4,
                                                unsigned short* __restrict__ SP2) {
  __shared__ __align__(16) unsigned short lds[16384];
  int tid = threadIdx.x, bn = blockIdx.x, bm = blockIdx.y;
  f32x4 acc[4][4];
  const unsigned short* Ab = Xs + (size_t)bm * 128 * 384;
  const unsigned short* Bb = Wsp + (size_t)bn * 128 * 384;
  gemm_core<6, 6>(Ab, 384, Ab, 384, Bb, 384, Bb, 384, lds, acc, tid);
  int lane = tid & 63, wid = tid >> 6, wm = wid & 1, wn = wid >> 1;
  int c16 = lane & 15, q = lane >> 4;
  int cg = bn * 32 + wn * 16 + c16;
  f32x4 bb = *(const f32x4*)&b0p4[cg * 4];
#pragma unroll
  for (int mf = 0; mf < 4; ++mf) {
    int row0 = bm * 128 + wm * 64 + mf * 16 + q * 4;
#pragma unroll
    for (int r = 0; r < 4; ++r) {
      u16x4 v;
      v.x = f2bf(acc[mf][0][r] + bb.x);
      v.y = f2bf(acc[mf][1][r] + bb.y);
      v.z = f2bf(acc[mf][2][r] + bb.z);
      v.w = f2bf(acc[mf][3][r] + bb.w);
      ((u16x4*)SP2)[(size_t)(row0 + r) * 512 + cg] = v;
    }
  }
}

// XCD swizzle: linear block l -> (bn, bm) with all 16 bn of one bm on XCD bm&7
// (dispatch heuristic: block l lands on XCD l%8).
DEVI void swz(int l, int& bn, int& bm) {
  int xcd = l & 7, i = l >> 3;     // i in 0..351
  bn = i & 15;
  bm = xcd + 8 * (i >> 4);         // 22 bm per xcd
}

// ---------------- per-step ----------------
// S1: gates0 = h0_prev @ W0p^T (+ static) + pos@Wpos^T ; cell0 -> h0 into nxt[:,0:512]
// c0 layout: [cg][row] -> f32x4 per mf.
template <bool USE_SP>
__global__ __launch_bounds__(256) void k_s1(const unsigned short* __restrict__ cur,
                                            const unsigned short* __restrict__ Xs,
                                            const unsigned short* __restrict__ W0p,
                                            const unsigned short* __restrict__ Wsp,
                                            const unsigned short* __restrict__ SP2,
                                            const float* __restrict__ b0p4,
                                            const float* __restrict__ Wposx,
                                            const float* __restrict__ Wposy,
                                            const float* __restrict__ posb,
                                            float* __restrict__ c0,
                                            unsigned short* __restrict__ nxt) {
  __shared__ __align__(16) unsigned short lds[16384];
  int tid = threadIdx.x, bn, bm;
  swz(blockIdx.x, bn, bm);
  f32x4 acc[4][4];
  const unsigned short* A1 = cur + (size_t)bm * 128 * 1024;
  const unsigned short* B1 = W0p + (size_t)bn * 128 * 512;
  if constexpr (USE_SP) {
    gemm_core<8, 8>(A1, 1024, A1, 1024, B1, 512, B1, 512, lds, acc, tid);
  } else {
    const unsigned short* A2 = Xs + (size_t)bm * 128 * 384;
    const unsigned short* B2 = Wsp + (size_t)bn * 128 * 384;
    gemm_core<14, 8>(A1, 1024, A2, 384, B1, 512, B2, 384, lds, acc, tid);
  }
  int lane = tid & 63, wid = tid >> 6, wm = wid & 1, wn = wid >> 1;
  int c16 = lane & 15, q = lane >> 4;
  int cg = bn * 32 + wn * 16 + c16;
  f32x4 wpx = *(const f32x4*)&Wposx[cg * 4];
  f32x4 wpy = *(const f32x4*)&Wposy[cg * 4];
  f32x4 sb = f32x4{0.f, 0.f, 0.f, 0.f};
  if constexpr (!USE_SP) sb = *(const f32x4*)&b0p4[cg * 4];
#pragma unroll
  for (int mf = 0; mf < 4; ++mf) {
    int row0 = bm * 128 + wm * 64 + mf * 16 + q * 4;
    f32x4 cold = *(const f32x4*)&c0[(size_t)cg * NROWS + row0];
    f32x4 cnew;
#pragma unroll
    for (int r = 0; r < 4; ++r) {
      size_t row = row0 + r;
      f32x2 pv = *(const f32x2*)&posb[row * 2];
      float s0 = sb.x, s1 = sb.y, s2 = sb.z, s3 = sb.w;
      if constexpr (USE_SP) {
        u16x4 sp = ((const u16x4*)SP2)[row * 512 + cg];
        s0 = bf2f(sp.x); s1 = bf2f(sp.y); s2 = bf2f(sp.z); s3 = bf2f(sp.w);
      }
      float gi = acc[mf][0][r] + s0 + pv.x * wpx.x + pv.y * wpy.x;
      float gf = acc[mf][1][r] + s1 + pv.x * wpx.y + pv.y * wpy.y;
      float gg = acc[mf][2][r] + s2 + pv.x * wpx.z + pv.y * wpy.z;
      float go = acc[mf][3][r] + s3 + pv.x * wpx.w + pv.y * wpy.w;
      float cn = fast_sigmoid(gf) * cold[r] + fast_sigmoid(gi) * fast_tanh(gg);
      cnew[r] = cn;
      nxt[row * 1024 + cg] = f2bf(fast_sigmoid(go) * fast_tanh(cn));
    }
    *(f32x4*)&c0[(size_t)cg * NROWS + row0] = cnew;
  }
}

// S2: gates1 = [h0_t | h1_prev] @ Wc1p^T + b1 ; cell1 -> h1 into nxt[:,512:]
__global__ __launch_bounds__(256) void k_s2(const unsigned short* __restrict__ nxt_in,
                                            const unsigned short* __restrict__ cur,
                                            const unsigned short* __restrict__ Wc1p,
                                            const float* __restrict__ b1p4,
                                            float* __restrict__ c1,
                                            unsigned short* __restrict__ nxt_out) {
  __shared__ __align__(16) unsigned short lds[16384];
  int tid = threadIdx.x, bn, bm;
  swz(blockIdx.x, bn, bm);
  f32x4 acc[4][4];
  const unsigned short* A1 = nxt_in + (size_t)bm * 128 * 1024;        // h0_t
  const unsigned short* A2 = cur + (size_t)bm * 128 * 1024 + 512;     // h1_{t-1}
  const unsigned short* B1 = Wc1p + (size_t)bn * 128 * 1024;
  gemm_core<16, 8>(A1, 1024, A2, 1024, B1, 1024, B1 + 512, 1024, lds, acc, tid);
  int lane = tid & 63, wid = tid >> 6, wm = wid & 1, wn = wid >> 1;
  int c16 = lane & 15, q = lane >> 4;
  int cg = bn * 32 + wn * 16 + c16;
  f32x4 bv = *(const f32x4*)&b1p4[cg * 4];
#pragma unroll
  for (int mf = 0; mf < 4; ++mf) {
    int row0 = bm * 128 + wm * 64 + mf * 16 + q * 4;
    f32x4 cold = *(const f32x4*)&c1[(size_t)cg * NROWS + row0];
    f32x4 cnew;
#pragma unroll
    for (int r = 0; r < 4; ++r) {
      size_t row = row0 + r;
      float gi = acc[mf][0][r] + bv.x;
      float gf = acc[mf][1][r] + bv.y;
      float gg = acc[mf][2][r] + bv.z;
      float go = acc[mf][3][r] + bv.w;
      float cn = fast_sigmoid(gf) * cold[r] + fast_sigmoid(gi) * fast_tanh(gg);
      cnew[r] = cn;
      nxt_out[row * 1024 + 512 + cg] = f2bf(fast_sigmoid(go) * fast_tanh(cn));
    }
    *(f32x4*)&c1[(size_t)cg * NROWS + row0] = cnew;
  }
}

// S3: pos = relu(h1 @ Wfc1^T + bfc1) @ Wfc2^T + bfc2 ; write preds[:,t], posb.
// 64 rows x 256 cols/block; fc2 via in-register partial dots + shfl_xor reduce.
// Swizzled so a block shares the XCD of the k_s2 blocks that produced its rows.
__global__ __launch_bounds__(256) void k_s3(const unsigned short* __restrict__ H,
                                            const unsigned short* __restrict__ Wfc1b,
                                            const float* __restrict__ bfc1,
                                            const float* __restrict__ Wfc2,
                                            const float* __restrict__ bfc2,
                                            float* __restrict__ out, float* __restrict__ posb,
                                            int t) {
  __shared__ __align__(16) unsigned short ldsA[64 * 64];    // 8 KB
  __shared__ __align__(16) unsigned short ldsB[256 * 64];   // 32 KB
  __shared__ float wfc2s[512];
  __shared__ float red[64 * 4];
  int tid = threadIdx.x;
  int l = blockIdx.x, xcd = l & 7, j = l >> 3;              // j in 0..43
  int bm = 2 * (xcd + 8 * (j >> 1)) + (j & 1);              // parent s2-bm on same xcd
  wfc2s[tid] = Wfc2[tid];
  wfc2s[tid + 256] = Wfc2[tid + 256];
  int lane = tid & 63, wid = tid >> 6, wm = wid & 1, wn = wid >> 1;
  int c16 = lane & 15, q = lane >> 4;
  f32x4 acc[2][8];
#pragma unroll
  for (int i = 0; i < 2; ++i)
#pragma unroll
    for (int jj = 0; jj < 8; ++jj) acc[i][jj] = f32x4{0.f, 0.f, 0.f, 0.f};
  const unsigned short* Ab = H + (size_t)bm * 64 * 1024 + 512;
  for (int kt = 0; kt < 8; ++kt) {
    int k0 = kt * 64;
    __syncthreads();
#pragma unroll
    for (int rd = 0; rd < 2; ++rd) {
      int p = rd * 256 + tid;
      int row = p >> 3, u = p & 7, ch = u ^ (row & 7);
      async_copy16(Ab + row * 1024 + k0 + ch * 8, ldsA + p * 8);
    }
#pragma unroll
    for (int rd = 0; rd < 8; ++rd) {
      int p = rd * 256 + tid;
      int row = p >> 3, u = p & 7, ch = u ^ (row & 7);
      async_copy16(Wfc1b + row * 512 + k0 + ch * 8, ldsB + p * 8);
    }
    __syncthreads();
#pragma unroll
    for (int s = 0; s < 2; ++s) {
      bf16x8 a[2], b[8];
#pragma unroll
      for (int mf = 0; mf < 2; ++mf) {
        int row = wm * 32 + mf * 16 + c16;
        int slot = row * 8 + ((s * 4 + q) ^ (row & 7));
        a[mf] = *(const bf16x8*)(ldsA + slot * 8);
      }
#pragma unroll
      for (int nf = 0; nf < 8; ++nf) {
        int row = wn * 128 + nf * 16 + c16;
        int slot = row * 8 + ((s * 4 + q) ^ (row & 7));
        b[nf] = *(const bf16x8*)(ldsB + slot * 8);
      }
#pragma unroll
      for (int mf = 0; mf < 2; ++mf)
#pragma unroll
        for (int nf = 0; nf < 8; ++nf)
          acc[mf][nf] = __builtin_amdgcn_mfma_f32_16x16x32_bf16(a[mf], b[nf], acc[mf][nf], 0, 0, 0);
    }
  }
  float part[2][2][4];   // [d][mf][r]
#pragma unroll
  for (int d = 0; d < 2; ++d)
#pragma unroll
    for (int mf = 0; mf < 2; ++mf)
#pragma unroll
      for (int r = 0; r < 4; ++r) part[d][mf][r] = 0.f;
#pragma unroll
  for (int nf = 0; nf < 8; ++nf) {
    int col = wn * 128 + nf * 16 + c16;
    float w0 = wfc2s[col], w1 = wfc2s[256 + col], bv = bfc1[col];
#pragma unroll
    for (int mf = 0; mf < 2; ++mf)
#pragma unroll
      for (int r = 0; r < 4; ++r) {
        float v = acc[mf][nf][r] + bv;
        v = v > 0.f ? v : 0.f;
        part[0][mf][r] += v * w0;
        part[1][mf][r] += v * w1;
      }
  }
#pragma unroll
  for (int st = 1; st < 16; st <<= 1)
#pragma unroll
    for (int d = 0; d < 2; ++d)
#pragma unroll
      for (int mf = 0; mf < 2; ++mf)
#pragma unroll
        for (int r = 0; r < 4; ++r)
          part[d][mf][r] += __shfl_xor(part[d][mf][r], st, 64);
  if (c16 == 0) {
#pragma unroll
    for (int mf = 0; mf < 2; ++mf)
#pragma unroll
      for (int r = 0; r < 4; ++r) {
        int rl = wm * 32 + mf * 16 + q * 4 + r;
        red[rl * 4 + wn * 2 + 0] = part[0][mf][r];
        red[rl * 4 + wn * 2 + 1] = part[1][mf][r];
      }
  }
  __syncthreads();
  if (tid < 128) {
    int rl = tid >> 1, d = tid & 1;
    float s = red[rl * 4 + d] + red[rl * 4 + 2 + d] + bfc2[d];
    int rg = bm * 64 + rl;
    out[((size_t)rg * T_STEPS + t) * 2 + d] = s;
    posb[rg * 2 + d] = s;
  }
}

// ---------------- launch ----------------
extern "C" void kernel_launch(void* const* d_in, const int* in_sizes, int n_in,
                              void* d_out, int out_size, void* d_ws, size_t ws_size,
                              hipStream_t stream) {
  (void)in_sizes; (void)n_in; (void)out_size;
  const float* ctx   = (const float*)d_in[0];
  const float* pos0  = (const float*)d_in[1];
  const float* ball  = (const float*)d_in[2];
  const int*   roles = (const int*)d_in[3];
  const float* role_table = (const float*)d_in[5];
  const float* Wih0 = (const float*)d_in[6];
  const float* Whh0 = (const float*)d_in[7];
  const float* b0   = (const float*)d_in[8];
  const float* Wih1 = (const float*)d_in[9];
  const float* Whh1 = (const float*)d_in[10];
  const float* b1   = (const float*)d_in[11];
  const float* Wfc1 = (const float*)d_in[12];
  const float* bfc1 = (const float*)d_in[13];
  const float* Wfc2 = (const float*)d_in[14];
  const float* bfc2 = (const float*)d_in[15];
  const float* Winit = (const float*)d_in[16];
  const float* binit = (const float*)d_in[17];
  float* out = (float*)d_out;

  char* w = (char*)d_ws;
  size_t used = 0;
  auto alloc = [&](size_t bytes) {
    char* p = w + used;
    used += (bytes + 255) & ~(size_t)255;
    return p;
  };
  unsigned short* W0p   = (unsigned short*)alloc((size_t)2048 * 512 * 2);
  unsigned short* Wc1p  = (unsigned short*)alloc((size_t)2048 * 1024 * 2);
  unsigned short* Wfc1b = (unsigned short*)alloc((size_t)256 * 512 * 2);
  float* Wposx = (float*)alloc(2048 * 4);
  float* Wposy = (float*)alloc(2048 * 4);
  float* b0p4  = (float*)alloc(2048 * 4);
  float* b1p4  = (float*)alloc(2048 * 4);
  float* posb  = (float*)alloc((size_t)NROWS * 2 * 4);
  unsigned short* Hc0 = (unsigned short*)alloc((size_t)NROWS * 1024 * 2);
  float* c0   = (float*)alloc((size_t)NROWS * 512 * 4);
  float* c1   = (float*)alloc((size_t)NROWS * 512 * 4);
  unsigned short* Hc1 = (unsigned short*)alloc((size_t)NROWS * 1024 * 2);

  const size_t SP_BYTES = (size_t)NROWS * 2048 * 2;           // 92.3 MB
  const bool use_sp = (ws_size >= used + SP_BYTES + (1u << 20));

  unsigned short *Xs, *Wsp, *SP2;
  if (use_sp) {
    SP2 = (unsigned short*)alloc(SP_BYTES);
    Xs  = Hc1;                                 // transient: dead before Hc1 is written
    Wsp = Hc1 + (size_t)NROWS * 384;
  } else {
    SP2 = Hc1;                                 // never dereferenced on lite path
    Xs  = (unsigned short*)alloc((size_t)NROWS * 384 * 2);
    Wsp = (unsigned short*)alloc((size_t)2048 * 384 * 2);
  }

  k_prep_w<<<2048, 512, 0, stream>>>(Whh0, Wih1, Whh1, Wih0, Wfc1, b0, b1,
                                     W0p, Wc1p, Wsp, Wfc1b, Wposx, Wposy, b0p4, b1p4);
  k_init_xs<<<NROWS, 384, 0, stream>>>(ball, ctx, roles, role_table, Xs);
  k_init_state<<<(NROWS * 512 + 255) / 256, 256, 0, stream>>>(pos0, Winit, binit, Hc0, c0, c1, posb);

  if (use_sp) {
    dim3 gs(16, NBM);
    k_static<<<gs, 256, 0, stream>>>(Xs, Wsp, b0p4, SP2);
  }

  for (int t = 0; t < T_STEPS; ++t) {
    unsigned short* cur = (t & 1) ? Hc1 : Hc0;
    unsigned short* nxt = (t & 1) ? Hc0 : Hc1;
    if (use_sp)
      k_s1<true><<<16 * NBM, 256, 0, stream>>>(cur, Xs, W0p, Wsp, SP2, b0p4, Wposx, Wposy, posb, c0, nxt);
    else
      k_s1<false><<<16 * NBM, 256, 0, stream>>>(cur, Xs, W0p, Wsp, SP2, b0p4, Wposx, Wposy, posb, c0, nxt);
    k_s2<<<16 * NBM, 256, 0, stream>>>(nxt, cur, Wc1p, b1p4, c1, nxt);
    k_s3<<<352, 256, 0, stream>>>(nxt, Wfc1b, bfc1, Wfc2, bfc2, out, posb, t);
  }
}

// Round 7
// 22642.371 us; speedup vs baseline: 3.8413x; 1.2013x over previous
//
#include <hip/hip_runtime.h>
#include <cstdint>

// RoleConditionedLSTMDecoder on MI355X (gfx950) — R7.
// = R6 (27.2 ms) + FULL UNROLL of all GEMM kt loops: KITERS/KSWITCH are template
//   constants, so unrolling constant-folds the A1/A2 selects and strength-reduces
//   the staging address math (m98: VALUBusy 43% on this structure, ~21 addr insts
//   per kt in the m97 disasm — the co-dominant consumer next to MFMA 37%).
// Arithmetic untouched -> absmax must stay bit-identical (0.007354736).
// Gate-permuted weight rows: perm j = tile*128 + half*64 + gate*16 + c16
// (h-col = tile*32 + half*16 + c16) -> lane's 4 col-frags = i,f,g,o of one (row,h-col).

#define DEVI __device__ __forceinline__

typedef __bf16 bf16x8 __attribute__((ext_vector_type(8)));
typedef float  f32x4  __attribute__((ext_vector_type(4)));
typedef float  f32x2  __attribute__((ext_vector_type(2)));
typedef unsigned short u16x4 __attribute__((ext_vector_type(4)));

static constexpr int NROWS = 22528;   // B*P
static constexpr int T_STEPS = 100;
static constexpr int NBM = 176;       // 22528/128 row-tiles

DEVI unsigned short f2bf(float f) {
  unsigned u = __float_as_uint(f);
  u = u + 0x7FFFu + ((u >> 16) & 1u);   // RNE
  return (unsigned short)(u >> 16);
}
DEVI float bf2f(unsigned short h) { return __uint_as_float(((unsigned)h) << 16); }

DEVI float fast_sigmoid(float x) {
  float e = __builtin_amdgcn_exp2f(-1.442695041f * x);
  return __builtin_amdgcn_rcpf(1.0f + e);
}
DEVI float fast_tanh(float x) {
  float e = __builtin_amdgcn_exp2f(2.885390082f * x);   // e^(2x)
  return 1.0f - 2.0f * __builtin_amdgcn_rcpf(e + 1.0f);
}

DEVI void async_copy16(const void* g, void* l) {
  __builtin_amdgcn_global_load_lds(
      (const __attribute__((address_space(1))) void*)g,
      (__attribute__((address_space(3))) void*)l, 16, 0, 0);
}

// ---------------- 128x128 GEMM core (BK=64, 256 thr, 4 waves 2x2) — proven ----------------
// kt loop FULLY UNROLLED: sec-selects fold, staging addresses become base+const.
template <int KITERS, int KSWITCH>
DEVI void gemm_core(const unsigned short* __restrict__ A1, int lda1,
                    const unsigned short* __restrict__ A2, int lda2,
                    const unsigned short* __restrict__ B1, int ldb1,
                    const unsigned short* __restrict__ B2, int ldb2,
                    unsigned short* lds, f32x4 acc[4][4], int tid) {
  const int lane = tid & 63, wid = tid >> 6;
  const int wm = wid & 1, wn = wid >> 1;
  const int c16 = lane & 15, q = lane >> 4;
#pragma unroll
  for (int i = 0; i < 4; ++i)
#pragma unroll
    for (int j = 0; j < 4; ++j) acc[i][j] = f32x4{0.f, 0.f, 0.f, 0.f};
#pragma unroll
  for (int kt = 0; kt < KITERS; ++kt) {
    const bool sec = (kt >= KSWITCH);
    const unsigned short* Ab = sec ? A2 : A1;
    const unsigned short* Bb = sec ? B2 : B1;
    const int lda = sec ? lda2 : lda1;
    const int ldb = sec ? ldb2 : ldb1;
    const int kk = (sec ? (kt - KSWITCH) : kt) * 64;
    __syncthreads();                       // prior reads done before overwrite
#pragma unroll
    for (int rd = 0; rd < 4; ++rd) {
      int p = rd * 256 + tid;
      int row = p >> 3, u = p & 7, ch = u ^ (row & 7);
      async_copy16(Ab + row * lda + kk + ch * 8, lds + p * 8);
      async_copy16(Bb + row * ldb + kk + ch * 8, lds + 8192 + p * 8);
    }
    __syncthreads();
#pragma unroll
    for (int s = 0; s < 2; ++s) {
      bf16x8 a[4], b[4];
#pragma unroll
      for (int mf = 0; mf < 4; ++mf) {
        int row = wm * 64 + mf * 16 + c16;
        int slot = row * 8 + ((s * 4 + q) ^ (row & 7));
        a[mf] = *(const bf16x8*)(lds + slot * 8);
      }
#pragma unroll
      for (int nf = 0; nf < 4; ++nf) {
        int row = wn * 64 + nf * 16 + c16;
        int slot = row * 8 + ((s * 4 + q) ^ (row & 7));
        b[nf] = *(const bf16x8*)(lds + 8192 + slot * 8);
      }
#pragma unroll
      for (int mf = 0; mf < 4; ++mf)
#pragma unroll
        for (int nf = 0; nf < 4; ++nf)
          acc[mf][nf] = __builtin_amdgcn_mfma_f32_16x16x32_bf16(a[mf], b[nf], acc[mf][nf], 0, 0, 0);
    }
  }
}

// ---------------- prep ----------------
DEVI int orig_row(int j) {  // permuted gate-col -> original row of [4H x K] weight
  int tile = j >> 7, rem = j & 127;
  int half = rem >> 6, g = (rem >> 4) & 3, cc = rem & 15;
  return g * 512 + (tile * 32 + half * 16 + cc);
}

__global__ void k_prep_w(const float* __restrict__ Whh0, const float* __restrict__ Wih1,
                         const float* __restrict__ Whh1, const float* __restrict__ Wih0,
                         const float* __restrict__ Wfc1, const float* __restrict__ b0,
                         const float* __restrict__ b1,
                         unsigned short* __restrict__ W0p, unsigned short* __restrict__ Wc1p,
                         unsigned short* __restrict__ Wsp, unsigned short* __restrict__ Wfc1b,
                         float* __restrict__ Wposx, float* __restrict__ Wposy,
                         float* __restrict__ b0p4, float* __restrict__ b1p4) {
  int j = blockIdx.x;       // 0..2047
  int k = threadIdx.x;      // 0..511
  int o = orig_row(j);
  W0p[j * 512 + k]         = f2bf(Whh0[o * 512 + k]);
  Wc1p[j * 1024 + k]       = f2bf(Wih1[o * 512 + k]);
  Wc1p[j * 1024 + 512 + k] = f2bf(Whh1[o * 512 + k]);
  if (k < 384) Wsp[j * 384 + k] = (k < 322) ? f2bf(Wih0[o * 324 + 2 + k]) : (unsigned short)0;
  if (k == 0) {
    int g = (j >> 4) & 3;
    int cg = (j >> 7) * 32 + ((j >> 6) & 1) * 16 + (j & 15);
    Wposx[cg * 4 + g] = Wih0[o * 324 + 0];
    Wposy[cg * 4 + g] = Wih0[o * 324 + 1];
    b0p4[cg * 4 + g] = b0[o];
    b1p4[cg * 4 + g] = b1[o];
  }
  if (j < 256) Wfc1b[j * 512 + k] = f2bf(Wfc1[j * 512 + k]);
}

__global__ void k_init_xs(const float* __restrict__ ball, const float* __restrict__ ctx,
                          const int* __restrict__ roles, const float* __restrict__ role_table,
                          unsigned short* __restrict__ Xs) {
  int n = blockIdx.x, col = threadIdx.x;  // 22528 x 384
  int b = n / 22;
  float v;
  if (col < 2)        v = ball[b * 2 + col];
  else if (col < 258) v = ctx[(size_t)n * 256 + col - 2];
  else if (col < 322) v = role_table[roles[n] * 64 + col - 258];
  else                v = 0.f;
  Xs[(size_t)n * 384 + col] = f2bf(v);
}

__global__ void k_init_state(const float* __restrict__ pos0, const float* __restrict__ Winit,
                             const float* __restrict__ binit, unsigned short* __restrict__ Hcat,
                             float* __restrict__ c0, float* __restrict__ c1,
                             float* __restrict__ posb) {
  int idx = blockIdx.x * 256 + threadIdx.x;     // N*512
  if (idx >= NROWS * 512) return;
  int n = idx >> 9, c = idx & 511;
  float px = pos0[n * 2 + 0], py = pos0[n * 2 + 1];
  float h0 = binit[c] + Winit[c * 2 + 0] * px + Winit[c * 2 + 1] * py;
  Hcat[(size_t)n * 1024 + c] = f2bf(h0);
  Hcat[(size_t)n * 1024 + 512 + c] = 0;   // h1 = 0
  c0[idx] = 0.f;                          // [cg][row] layout; fully zeroed either way
  c1[idx] = 0.f;
  if (c < 2) posb[n * 2 + c] = pos0[n * 2 + c];
}

// static_proj packed: SP2[row*512+cg] = ushort4{i,f,g,o} + b0 — SP path only
__global__ __launch_bounds__(256) void k_static(const unsigned short* __restrict__ Xs,
                                                const unsigned short* __restrict__ Wsp,
                                                const float* __restrict__ b0p4,
                                                unsigned short* __restrict__ SP2) {
  __shared__ __align__(16) unsigned short lds[16384];
  int tid = threadIdx.x, bn = blockIdx.x, bm = blockIdx.y;
  f32x4 acc[4][4];
  const unsigned short* Ab = Xs + (size_t)bm * 128 * 384;
  const unsigned short* Bb = Wsp + (size_t)bn * 128 * 384;
  gemm_core<6, 6>(Ab, 384, Ab, 384, Bb, 384, Bb, 384, lds, acc, tid);
  int lane = tid & 63, wid = tid >> 6, wm = wid & 1, wn = wid >> 1;
  int c16 = lane & 15, q = lane >> 4;
  int cg = bn * 32 + wn * 16 + c16;
  f32x4 bb = *(const f32x4*)&b0p4[cg * 4];
#pragma unroll
  for (int mf = 0; mf < 4; ++mf) {
    int row0 = bm * 128 + wm * 64 + mf * 16 + q * 4;
#pragma unroll
    for (int r = 0; r < 4; ++r) {
      u16x4 v;
      v.x = f2bf(acc[mf][0][r] + bb.x);
      v.y = f2bf(acc[mf][1][r] + bb.y);
      v.z = f2bf(acc[mf][2][r] + bb.z);
      v.w = f2bf(acc[mf][3][r] + bb.w);
      ((u16x4*)SP2)[(size_t)(row0 + r) * 512 + cg] = v;
    }
  }
}

// XCD swizzle: linear block l -> (bn, bm) with all 16 bn of one bm on XCD bm&7.
DEVI void swz(int l, int& bn, int& bm) {
  int xcd = l & 7, i = l >> 3;     // i in 0..351
  bn = i & 15;
  bm = xcd + 8 * (i >> 4);         // 22 bm per xcd
}

// ---------------- per-step ----------------
// S1: gates0 = h0_prev @ W0p^T (+ static) + pos@Wpos^T ; cell0 -> h0 into nxt[:,0:512]
template <bool USE_SP>
__global__ __launch_bounds__(256) void k_s1(const unsigned short* __restrict__ cur,
                                            const unsigned short* __restrict__ Xs,
                                            const unsigned short* __restrict__ W0p,
                                            const unsigned short* __restrict__ Wsp,
                                            const unsigned short* __restrict__ SP2,
                                            const float* __restrict__ b0p4,
                                            const float* __restrict__ Wposx,
                                            const float* __restrict__ Wposy,
                                            const float* __restrict__ posb,
                                            float* __restrict__ c0,
                                            unsigned short* __restrict__ nxt) {
  __shared__ __align__(16) unsigned short lds[16384];
  int tid = threadIdx.x, bn, bm;
  swz(blockIdx.x, bn, bm);
  f32x4 acc[4][4];
  const unsigned short* A1 = cur + (size_t)bm * 128 * 1024;
  const unsigned short* B1 = W0p + (size_t)bn * 128 * 512;
  if constexpr (USE_SP) {
    gemm_core<8, 8>(A1, 1024, A1, 1024, B1, 512, B1, 512, lds, acc, tid);
  } else {
    const unsigned short* A2 = Xs + (size_t)bm * 128 * 384;
    const unsigned short* B2 = Wsp + (size_t)bn * 128 * 384;
    gemm_core<14, 8>(A1, 1024, A2, 384, B1, 512, B2, 384, lds, acc, tid);
  }
  int lane = tid & 63, wid = tid >> 6, wm = wid & 1, wn = wid >> 1;
  int c16 = lane & 15, q = lane >> 4;
  int cg = bn * 32 + wn * 16 + c16;
  f32x4 wpx = *(const f32x4*)&Wposx[cg * 4];
  f32x4 wpy = *(const f32x4*)&Wposy[cg * 4];
  f32x4 sb = f32x4{0.f, 0.f, 0.f, 0.f};
  if constexpr (!USE_SP) sb = *(const f32x4*)&b0p4[cg * 4];
#pragma unroll
  for (int mf = 0; mf < 4; ++mf) {
    int row0 = bm * 128 + wm * 64 + mf * 16 + q * 4;
    f32x4 cold = *(const f32x4*)&c0[(size_t)cg * NROWS + row0];
    f32x4 cnew;
#pragma unroll
    for (int r = 0; r < 4; ++r) {
      size_t row = row0 + r;
      f32x2 pv = *(const f32x2*)&posb[row * 2];
      float s0 = sb.x, s1 = sb.y, s2 = sb.z, s3 = sb.w;
      if constexpr (USE_SP) {
        u16x4 sp = ((const u16x4*)SP2)[row * 512 + cg];
        s0 = bf2f(sp.x); s1 = bf2f(sp.y); s2 = bf2f(sp.z); s3 = bf2f(sp.w);
      }
      float gi = acc[mf][0][r] + s0 + pv.x * wpx.x + pv.y * wpy.x;
      float gf = acc[mf][1][r] + s1 + pv.x * wpx.y + pv.y * wpy.y;
      float gg = acc[mf][2][r] + s2 + pv.x * wpx.z + pv.y * wpy.z;
      float go = acc[mf][3][r] + s3 + pv.x * wpx.w + pv.y * wpy.w;
      float cn = fast_sigmoid(gf) * cold[r] + fast_sigmoid(gi) * fast_tanh(gg);
      cnew[r] = cn;
      nxt[row * 1024 + cg] = f2bf(fast_sigmoid(go) * fast_tanh(cn));
    }
    *(f32x4*)&c0[(size_t)cg * NROWS + row0] = cnew;
  }
}

// S2: gates1 = [h0_t | h1_prev] @ Wc1p^T + b1 ; cell1 -> h1 into nxt[:,512:]
__global__ __launch_bounds__(256) void k_s2(const unsigned short* __restrict__ nxt_in,
                                            const unsigned short* __restrict__ cur,
                                            const unsigned short* __restrict__ Wc1p,
                                            const float* __restrict__ b1p4,
                                            float* __restrict__ c1,
                                            unsigned short* __restrict__ nxt_out) {
  __shared__ __align__(16) unsigned short lds[16384];
  int tid = threadIdx.x, bn, bm;
  swz(blockIdx.x, bn, bm);
  f32x4 acc[4][4];
  const unsigned short* A1 = nxt_in + (size_t)bm * 128 * 1024;        // h0_t
  const unsigned short* A2 = cur + (size_t)bm * 128 * 1024 + 512;     // h1_{t-1}
  const unsigned short* B1 = Wc1p + (size_t)bn * 128 * 1024;
  gemm_core<16, 8>(A1, 1024, A2, 1024, B1, 1024, B1 + 512, 1024, lds, acc, tid);
  int lane = tid & 63, wid = tid >> 6, wm = wid & 1, wn = wid >> 1;
  int c16 = lane & 15, q = lane >> 4;
  int cg = bn * 32 + wn * 16 + c16;
  f32x4 bv = *(const f32x4*)&b1p4[cg * 4];
#pragma unroll
  for (int mf = 0; mf < 4; ++mf) {
    int row0 = bm * 128 + wm * 64 + mf * 16 + q * 4;
    f32x4 cold = *(const f32x4*)&c1[(size_t)cg * NROWS + row0];
    f32x4 cnew;
#pragma unroll
    for (int r = 0; r < 4; ++r) {
      size_t row = row0 + r;
      float gi = acc[mf][0][r] + bv.x;
      float gf = acc[mf][1][r] + bv.y;
      float gg = acc[mf][2][r] + bv.z;
      float go = acc[mf][3][r] + bv.w;
      float cn = fast_sigmoid(gf) * cold[r] + fast_sigmoid(gi) * fast_tanh(gg);
      cnew[r] = cn;
      nxt_out[row * 1024 + 512 + cg] = f2bf(fast_sigmoid(go) * fast_tanh(cn));
    }
    *(f32x4*)&c1[(size_t)cg * NROWS + row0] = cnew;
  }
}

// S3: pos = relu(h1 @ Wfc1^T + bfc1) @ Wfc2^T + bfc2 ; write preds[:,t], posb.
__global__ __launch_bounds__(256) void k_s3(const unsigned short* __restrict__ H,
                                            const unsigned short* __restrict__ Wfc1b,
                                            const float* __restrict__ bfc1,
                                            const float* __restrict__ Wfc2,
                                            const float* __restrict__ bfc2,
                                            float* __restrict__ out, float* __restrict__ posb,
                                            int t) {
  __shared__ __align__(16) unsigned short ldsA[64 * 64];    // 8 KB
  __shared__ __align__(16) unsigned short ldsB[256 * 64];   // 32 KB
  __shared__ float wfc2s[512];
  __shared__ float red[64 * 4];
  int tid = threadIdx.x;
  int l = blockIdx.x, xcd = l & 7, j = l >> 3;              // j in 0..43
  int bm = 2 * (xcd + 8 * (j >> 1)) + (j & 1);              // parent s2-bm on same xcd
  wfc2s[tid] = Wfc2[tid];
  wfc2s[tid + 256] = Wfc2[tid + 256];
  int lane = tid & 63, wid = tid >> 6, wm = wid & 1, wn = wid >> 1;
  int c16 = lane & 15, q = lane >> 4;
  f32x4 acc[2][8];
#pragma unroll
  for (int i = 0; i < 2; ++i)
#pragma unroll
    for (int jj = 0; jj < 8; ++jj) acc[i][jj] = f32x4{0.f, 0.f, 0.f, 0.f};
  const unsigned short* Ab = H + (size_t)bm * 64 * 1024 + 512;
#pragma unroll
  for (int kt = 0; kt < 8; ++kt) {
    int k0 = kt * 64;
    __syncthreads();
#pragma unroll
    for (int rd = 0; rd < 2; ++rd) {
      int p = rd * 256 + tid;
      int row = p >> 3, u = p & 7, ch = u ^ (row & 7);
      async_copy16(Ab + row * 1024 + k0 + ch * 8, ldsA + p * 8);
    }
#pragma unroll
    for (int rd = 0; rd < 8; ++rd) {
      int p = rd * 256 + tid;
      int row = p >> 3, u = p & 7, ch = u ^ (row & 7);
      async_copy16(Wfc1b + row * 512 + k0 + ch * 8, ldsB + p * 8);
    }
    __syncthreads();
#pragma unroll
    for (int s = 0; s < 2; ++s) {
      bf16x8 a[2], b[8];
#pragma unroll
      for (int mf = 0; mf < 2; ++mf) {
        int row = wm * 32 + mf * 16 + c16;
        int slot = row * 8 + ((s * 4 + q) ^ (row & 7));
        a[mf] = *(const bf16x8*)(ldsA + slot * 8);
      }
#pragma unroll
      for (int nf = 0; nf < 8; ++nf) {
        int row = wn * 128 + nf * 16 + c16;
        int slot = row * 8 + ((s * 4 + q) ^ (row & 7));
        b[nf] = *(const bf16x8*)(ldsB + slot * 8);
      }
#pragma unroll
      for (int mf = 0; mf < 2; ++mf)
#pragma unroll
        for (int nf = 0; nf < 8; ++nf)
          acc[mf][nf] = __builtin_amdgcn_mfma_f32_16x16x32_bf16(a[mf], b[nf], acc[mf][nf], 0, 0, 0);
    }
  }
  float part[2][2][4];   // [d][mf][r]
#pragma unroll
  for (int d = 0; d < 2; ++d)
#pragma unroll
    for (int mf = 0; mf < 2; ++mf)
#pragma unroll
      for (int r = 0; r < 4; ++r) part[d][mf][r] = 0.f;
#pragma unroll
  for (int nf = 0; nf < 8; ++nf) {
    int col = wn * 128 + nf * 16 + c16;
    float w0 = wfc2s[col], w1 = wfc2s[256 + col], bv = bfc1[col];
#pragma unroll
    for (int mf = 0; mf < 2; ++mf)
#pragma unroll
      for (int r = 0; r < 4; ++r) {
        float v = acc[mf][nf][r] + bv;
        v = v > 0.f ? v : 0.f;
        part[0][mf][r] += v * w0;
        part[1][mf][r] += v * w1;
      }
  }
#pragma unroll
  for (int st = 1; st < 16; st <<= 1)
#pragma unroll
    for (int d = 0; d < 2; ++d)
#pragma unroll
      for (int mf = 0; mf < 2; ++mf)
#pragma unroll
        for (int r = 0; r < 4; ++r)
          part[d][mf][r] += __shfl_xor(part[d][mf][r], st, 64);
  if (c16 == 0) {
#pragma unroll
    for (int mf = 0; mf < 2; ++mf)
#pragma unroll
      for (int r = 0; r < 4; ++r) {
        int rl = wm * 32 + mf * 16 + q * 4 + r;
        red[rl * 4 + wn * 2 + 0] = part[0][mf][r];
        red[rl * 4 + wn * 2 + 1] = part[1][mf][r];
      }
  }
  __syncthreads();
  if (tid < 128) {
    int rl = tid >> 1, d = tid & 1;
    float s = red[rl * 4 + d] + red[rl * 4 + 2 + d] + bfc2[d];
    int rg = bm * 64 + rl;
    out[((size_t)rg * T_STEPS + t) * 2 + d] = s;
    posb[rg * 2 + d] = s;
  }
}

// ---------------- launch ----------------
extern "C" void kernel_launch(void* const* d_in, const int* in_sizes, int n_in,
                              void* d_out, int out_size, void* d_ws, size_t ws_size,
                              hipStream_t stream) {
  (void)in_sizes; (void)n_in; (void)out_size;
  const float* ctx   = (const float*)d_in[0];
  const float* pos0  = (const float*)d_in[1];
  const float* ball  = (const float*)d_in[2];
  const int*   roles = (const int*)d_in[3];
  const float* role_table = (const float*)d_in[5];
  const float* Wih0 = (const float*)d_in[6];
  const float* Whh0 = (const float*)d_in[7];
  const float* b0   = (const float*)d_in[8];
  const float* Wih1 = (const float*)d_in[9];
  const float* Whh1 = (const float*)d_in[10];
  const float* b1   = (const float*)d_in[11];
  const float* Wfc1 = (const float*)d_in[12];
  const float* bfc1 = (const float*)d_in[13];
  const float* Wfc2 = (const float*)d_in[14];
  const float* bfc2 = (const float*)d_in[15];
  const float* Winit = (const float*)d_in[16];
  const float* binit = (const float*)d_in[17];
  float* out = (float*)d_out;

  char* w = (char*)d_ws;
  size_t used = 0;
  auto alloc = [&](size_t bytes) {
    char* p = w + used;
    used += (bytes + 255) & ~(size_t)255;
    return p;
  };
  unsigned short* W0p   = (unsigned short*)alloc((size_t)2048 * 512 * 2);
  unsigned short* Wc1p  = (unsigned short*)alloc((size_t)2048 * 1024 * 2);
  unsigned short* Wfc1b = (unsigned short*)alloc((size_t)256 * 512 * 2);
  float* Wposx = (float*)alloc(2048 * 4);
  float* Wposy = (float*)alloc(2048 * 4);
  float* b0p4  = (float*)alloc(2048 * 4);
  float* b1p4  = (float*)alloc(2048 * 4);
  float* posb  = (float*)alloc((size_t)NROWS * 2 * 4);
  unsigned short* Hc0 = (unsigned short*)alloc((size_t)NROWS * 1024 * 2);
  float* c0   = (float*)alloc((size_t)NROWS * 512 * 4);
  float* c1   = (float*)alloc((size_t)NROWS * 512 * 4);
  unsigned short* Hc1 = (unsigned short*)alloc((size_t)NROWS * 1024 * 2);

  const size_t SP_BYTES = (size_t)NROWS * 2048 * 2;           // 92.3 MB
  const bool use_sp = (ws_size >= used + SP_BYTES + (1u << 20));

  unsigned short *Xs, *Wsp, *SP2;
  if (use_sp) {
    SP2 = (unsigned short*)alloc(SP_BYTES);
    Xs  = Hc1;                                 // transient: dead before Hc1 is written
    Wsp = Hc1 + (size_t)NROWS * 384;
  } else {
    SP2 = Hc1;                                 // never dereferenced on lite path
    Xs  = (unsigned short*)alloc((size_t)NROWS * 384 * 2);
    Wsp = (unsigned short*)alloc((size_t)2048 * 384 * 2);
  }

  k_prep_w<<<2048, 512, 0, stream>>>(Whh0, Wih1, Whh1, Wih0, Wfc1, b0, b1,
                                     W0p, Wc1p, Wsp, Wfc1b, Wposx, Wposy, b0p4, b1p4);
  k_init_xs<<<NROWS, 384, 0, stream>>>(ball, ctx, roles, role_table, Xs);
  k_init_state<<<(NROWS * 512 + 255) / 256, 256, 0, stream>>>(pos0, Winit, binit, Hc0, c0, c1, posb);

  if (use_sp) {
    dim3 gs(16, NBM);
    k_static<<<gs, 256, 0, stream>>>(Xs, Wsp, b0p4, SP2);
  }

  for (int t = 0; t < T_STEPS; ++t) {
    unsigned short* cur = (t & 1) ? Hc1 : Hc0;
    unsigned short* nxt = (t & 1) ? Hc0 : Hc1;
    if (use_sp)
      k_s1<true><<<16 * NBM, 256, 0, stream>>>(cur, Xs, W0p, Wsp, SP2, b0p4, Wposx, Wposy, posb, c0, nxt);
    else
      k_s1<false><<<16 * NBM, 256, 0, stream>>>(cur, Xs, W0p, Wsp, SP2, b0p4, Wposx, Wposy, posb, c0, nxt);
    k_s2<<<16 * NBM, 256, 0, stream>>>(nxt, cur, Wc1p, b1p4, c1, nxt);
    k_s3<<<352, 256, 0, stream>>>(nxt, Wfc1b, bfc1, Wfc2, bfc2, out, posb, t);
  }
}

// Round 8
// 21708.195 us; speedup vs baseline: 4.0066x; 1.0430x over previous
//
#include <hip/hip_runtime.h>
#include <cstdint>

// RoleConditionedLSTMDecoder on MI355X (gfx950) — R8.
// = R7 (22.64 ms: unrolled kt loops) + S3 split 352x64row -> 704x32row blocks:
//   S3 was 1.4 blocks/CU — a latency-bound straggler alone on the critical path
//   each step. 704 blocks halves per-dispatch latency; Wfc1 restage still trivial.
// Gate-permuted weight rows: perm j = tile*128 + half*64 + gate*16 + c16
// (h-col = tile*32 + half*16 + c16) -> lane's 4 col-frags = i,f,g,o of one (row,h-col).

#define DEVI __device__ __forceinline__

typedef __bf16 bf16x8 __attribute__((ext_vector_type(8)));
typedef float  f32x4  __attribute__((ext_vector_type(4)));
typedef float  f32x2  __attribute__((ext_vector_type(2)));
typedef unsigned short u16x4 __attribute__((ext_vector_type(4)));

static constexpr int NROWS = 22528;   // B*P
static constexpr int T_STEPS = 100;
static constexpr int NBM = 176;       // 22528/128 row-tiles

DEVI unsigned short f2bf(float f) {
  unsigned u = __float_as_uint(f);
  u = u + 0x7FFFu + ((u >> 16) & 1u);   // RNE
  return (unsigned short)(u >> 16);
}
DEVI float bf2f(unsigned short h) { return __uint_as_float(((unsigned)h) << 16); }

DEVI float fast_sigmoid(float x) {
  float e = __builtin_amdgcn_exp2f(-1.442695041f * x);
  return __builtin_amdgcn_rcpf(1.0f + e);
}
DEVI float fast_tanh(float x) {
  float e = __builtin_amdgcn_exp2f(2.885390082f * x);   // e^(2x)
  return 1.0f - 2.0f * __builtin_amdgcn_rcpf(e + 1.0f);
}

DEVI void async_copy16(const void* g, void* l) {
  __builtin_amdgcn_global_load_lds(
      (const __attribute__((address_space(1))) void*)g,
      (__attribute__((address_space(3))) void*)l, 16, 0, 0);
}

// ---------------- 128x128 GEMM core (BK=64, 256 thr, 4 waves 2x2) — proven ----------------
// kt loop FULLY UNROLLED (R7): sec-selects fold, staging addresses become base+const.
template <int KITERS, int KSWITCH>
DEVI void gemm_core(const unsigned short* __restrict__ A1, int lda1,
                    const unsigned short* __restrict__ A2, int lda2,
                    const unsigned short* __restrict__ B1, int ldb1,
                    const unsigned short* __restrict__ B2, int ldb2,
                    unsigned short* lds, f32x4 acc[4][4], int tid) {
  const int lane = tid & 63, wid = tid >> 6;
  const int wm = wid & 1, wn = wid >> 1;
  const int c16 = lane & 15, q = lane >> 4;
#pragma unroll
  for (int i = 0; i < 4; ++i)
#pragma unroll
    for (int j = 0; j < 4; ++j) acc[i][j] = f32x4{0.f, 0.f, 0.f, 0.f};
#pragma unroll
  for (int kt = 0; kt < KITERS; ++kt) {
    const bool sec = (kt >= KSWITCH);
    const unsigned short* Ab = sec ? A2 : A1;
    const unsigned short* Bb = sec ? B2 : B1;
    const int lda = sec ? lda2 : lda1;
    const int ldb = sec ? ldb2 : ldb1;
    const int kk = (sec ? (kt - KSWITCH) : kt) * 64;
    __syncthreads();                       // prior reads done before overwrite
#pragma unroll
    for (int rd = 0; rd < 4; ++rd) {
      int p = rd * 256 + tid;
      int row = p >> 3, u = p & 7, ch = u ^ (row & 7);
      async_copy16(Ab + row * lda + kk + ch * 8, lds + p * 8);
      async_copy16(Bb + row * ldb + kk + ch * 8, lds + 8192 + p * 8);
    }
    __syncthreads();
#pragma unroll
    for (int s = 0; s < 2; ++s) {
      bf16x8 a[4], b[4];
#pragma unroll
      for (int mf = 0; mf < 4; ++mf) {
        int row = wm * 64 + mf * 16 + c16;
        int slot = row * 8 + ((s * 4 + q) ^ (row & 7));
        a[mf] = *(const bf16x8*)(lds + slot * 8);
      }
#pragma unroll
      for (int nf = 0; nf < 4; ++nf) {
        int row = wn * 64 + nf * 16 + c16;
        int slot = row * 8 + ((s * 4 + q) ^ (row & 7));
        b[nf] = *(const bf16x8*)(lds + 8192 + slot * 8);
      }
#pragma unroll
      for (int mf = 0; mf < 4; ++mf)
#pragma unroll
        for (int nf = 0; nf < 4; ++nf)
          acc[mf][nf] = __builtin_amdgcn_mfma_f32_16x16x32_bf16(a[mf], b[nf], acc[mf][nf], 0, 0, 0);
    }
  }
}

// ---------------- prep ----------------
DEVI int orig_row(int j) {  // permuted gate-col -> original row of [4H x K] weight
  int tile = j >> 7, rem = j & 127;
  int half = rem >> 6, g = (rem >> 4) & 3, cc = rem & 15;
  return g * 512 + (tile * 32 + half * 16 + cc);
}

__global__ void k_prep_w(const float* __restrict__ Whh0, const float* __restrict__ Wih1,
                         const float* __restrict__ Whh1, const float* __restrict__ Wih0,
                         const float* __restrict__ Wfc1, const float* __restrict__ b0,
                         const float* __restrict__ b1,
                         unsigned short* __restrict__ W0p, unsigned short* __restrict__ Wc1p,
                         unsigned short* __restrict__ Wsp, unsigned short* __restrict__ Wfc1b,
                         float* __restrict__ Wposx, float* __restrict__ Wposy,
                         float* __restrict__ b0p4, float* __restrict__ b1p4) {
  int j = blockIdx.x;       // 0..2047
  int k = threadIdx.x;      // 0..511
  int o = orig_row(j);
  W0p[j * 512 + k]         = f2bf(Whh0[o * 512 + k]);
  Wc1p[j * 1024 + k]       = f2bf(Wih1[o * 512 + k]);
  Wc1p[j * 1024 + 512 + k] = f2bf(Whh1[o * 512 + k]);
  if (k < 384) Wsp[j * 384 + k] = (k < 322) ? f2bf(Wih0[o * 324 + 2 + k]) : (unsigned short)0;
  if (k == 0) {
    int g = (j >> 4) & 3;
    int cg = (j >> 7) * 32 + ((j >> 6) & 1) * 16 + (j & 15);
    Wposx[cg * 4 + g] = Wih0[o * 324 + 0];
    Wposy[cg * 4 + g] = Wih0[o * 324 + 1];
    b0p4[cg * 4 + g] = b0[o];
    b1p4[cg * 4 + g] = b1[o];
  }
  if (j < 256) Wfc1b[j * 512 + k] = f2bf(Wfc1[j * 512 + k]);
}

__global__ void k_init_xs(const float* __restrict__ ball, const float* __restrict__ ctx,
                          const int* __restrict__ roles, const float* __restrict__ role_table,
                          unsigned short* __restrict__ Xs) {
  int n = blockIdx.x, col = threadIdx.x;  // 22528 x 384
  int b = n / 22;
  float v;
  if (col < 2)        v = ball[b * 2 + col];
  else if (col < 258) v = ctx[(size_t)n * 256 + col - 2];
  else if (col < 322) v = role_table[roles[n] * 64 + col - 258];
  else                v = 0.f;
  Xs[(size_t)n * 384 + col] = f2bf(v);
}

__global__ void k_init_state(const float* __restrict__ pos0, const float* __restrict__ Winit,
                             const float* __restrict__ binit, unsigned short* __restrict__ Hcat,
                             float* __restrict__ c0, float* __restrict__ c1,
                             float* __restrict__ posb) {
  int idx = blockIdx.x * 256 + threadIdx.x;     // N*512
  if (idx >= NROWS * 512) return;
  int n = idx >> 9, c = idx & 511;
  float px = pos0[n * 2 + 0], py = pos0[n * 2 + 1];
  float h0 = binit[c] + Winit[c * 2 + 0] * px + Winit[c * 2 + 1] * py;
  Hcat[(size_t)n * 1024 + c] = f2bf(h0);
  Hcat[(size_t)n * 1024 + 512 + c] = 0;   // h1 = 0
  c0[idx] = 0.f;                          // [cg][row] layout; fully zeroed either way
  c1[idx] = 0.f;
  if (c < 2) posb[n * 2 + c] = pos0[n * 2 + c];
}

// static_proj packed: SP2[row*512+cg] = ushort4{i,f,g,o} + b0 — SP path only
__global__ __launch_bounds__(256) void k_static(const unsigned short* __restrict__ Xs,
                                                const unsigned short* __restrict__ Wsp,
                                                const float* __restrict__ b0p4,
                                                unsigned short* __restrict__ SP2) {
  __shared__ __align__(16) unsigned short lds[16384];
  int tid = threadIdx.x, bn = blockIdx.x, bm = blockIdx.y;
  f32x4 acc[4][4];
  const unsigned short* Ab = Xs + (size_t)bm * 128 * 384;
  const unsigned short* Bb = Wsp + (size_t)bn * 128 * 384;
  gemm_core<6, 6>(Ab, 384, Ab, 384, Bb, 384, Bb, 384, lds, acc, tid);
  int lane = tid & 63, wid = tid >> 6, wm = wid & 1, wn = wid >> 1;
  int c16 = lane & 15, q = lane >> 4;
  int cg = bn * 32 + wn * 16 + c16;
  f32x4 bb = *(const f32x4*)&b0p4[cg * 4];
#pragma unroll
  for (int mf = 0; mf < 4; ++mf) {
    int row0 = bm * 128 + wm * 64 + mf * 16 + q * 4;
#pragma unroll
    for (int r = 0; r < 4; ++r) {
      u16x4 v;
      v.x = f2bf(acc[mf][0][r] + bb.x);
      v.y = f2bf(acc[mf][1][r] + bb.y);
      v.z = f2bf(acc[mf][2][r] + bb.z);
      v.w = f2bf(acc[mf][3][r] + bb.w);
      ((u16x4*)SP2)[(size_t)(row0 + r) * 512 + cg] = v;
    }
  }
}

// XCD swizzle: linear block l -> (bn, bm) with all 16 bn of one bm on XCD bm&7.
DEVI void swz(int l, int& bn, int& bm) {
  int xcd = l & 7, i = l >> 3;     // i in 0..351
  bn = i & 15;
  bm = xcd + 8 * (i >> 4);         // 22 bm per xcd
}

// ---------------- per-step ----------------
// S1: gates0 = h0_prev @ W0p^T (+ static) + pos@Wpos^T ; cell0 -> h0 into nxt[:,0:512]
template <bool USE_SP>
__global__ __launch_bounds__(256) void k_s1(const unsigned short* __restrict__ cur,
                                            const unsigned short* __restrict__ Xs,
                                            const unsigned short* __restrict__ W0p,
                                            const unsigned short* __restrict__ Wsp,
                                            const unsigned short* __restrict__ SP2,
                                            const float* __restrict__ b0p4,
                                            const float* __restrict__ Wposx,
                                            const float* __restrict__ Wposy,
                                            const float* __restrict__ posb,
                                            float* __restrict__ c0,
                                            unsigned short* __restrict__ nxt) {
  __shared__ __align__(16) unsigned short lds[16384];
  int tid = threadIdx.x, bn, bm;
  swz(blockIdx.x, bn, bm);
  f32x4 acc[4][4];
  const unsigned short* A1 = cur + (size_t)bm * 128 * 1024;
  const unsigned short* B1 = W0p + (size_t)bn * 128 * 512;
  if constexpr (USE_SP) {
    gemm_core<8, 8>(A1, 1024, A1, 1024, B1, 512, B1, 512, lds, acc, tid);
  } else {
    const unsigned short* A2 = Xs + (size_t)bm * 128 * 384;
    const unsigned short* B2 = Wsp + (size_t)bn * 128 * 384;
    gemm_core<14, 8>(A1, 1024, A2, 384, B1, 512, B2, 384, lds, acc, tid);
  }
  int lane = tid & 63, wid = tid >> 6, wm = wid & 1, wn = wid >> 1;
  int c16 = lane & 15, q = lane >> 4;
  int cg = bn * 32 + wn * 16 + c16;
  f32x4 wpx = *(const f32x4*)&Wposx[cg * 4];
  f32x4 wpy = *(const f32x4*)&Wposy[cg * 4];
  f32x4 sb = f32x4{0.f, 0.f, 0.f, 0.f};
  if constexpr (!USE_SP) sb = *(const f32x4*)&b0p4[cg * 4];
#pragma unroll
  for (int mf = 0; mf < 4; ++mf) {
    int row0 = bm * 128 + wm * 64 + mf * 16 + q * 4;
    f32x4 cold = *(const f32x4*)&c0[(size_t)cg * NROWS + row0];
    f32x4 cnew;
#pragma unroll
    for (int r = 0; r < 4; ++r) {
      size_t row = row0 + r;
      f32x2 pv = *(const f32x2*)&posb[row * 2];
      float s0 = sb.x, s1 = sb.y, s2 = sb.z, s3 = sb.w;
      if constexpr (USE_SP) {
        u16x4 sp = ((const u16x4*)SP2)[row * 512 + cg];
        s0 = bf2f(sp.x); s1 = bf2f(sp.y); s2 = bf2f(sp.z); s3 = bf2f(sp.w);
      }
      float gi = acc[mf][0][r] + s0 + pv.x * wpx.x + pv.y * wpy.x;
      float gf = acc[mf][1][r] + s1 + pv.x * wpx.y + pv.y * wpy.y;
      float gg = acc[mf][2][r] + s2 + pv.x * wpx.z + pv.y * wpy.z;
      float go = acc[mf][3][r] + s3 + pv.x * wpx.w + pv.y * wpy.w;
      float cn = fast_sigmoid(gf) * cold[r] + fast_sigmoid(gi) * fast_tanh(gg);
      cnew[r] = cn;
      nxt[row * 1024 + cg] = f2bf(fast_sigmoid(go) * fast_tanh(cn));
    }
    *(f32x4*)&c0[(size_t)cg * NROWS + row0] = cnew;
  }
}

// S2: gates1 = [h0_t | h1_prev] @ Wc1p^T + b1 ; cell1 -> h1 into nxt[:,512:]
__global__ __launch_bounds__(256) void k_s2(const unsigned short* __restrict__ nxt_in,
                                            const unsigned short* __restrict__ cur,
                                            const unsigned short* __restrict__ Wc1p,
                                            const float* __restrict__ b1p4,
                                            float* __restrict__ c1,
                                            unsigned short* __restrict__ nxt_out) {
  __shared__ __align__(16) unsigned short lds[16384];
  int tid = threadIdx.x, bn, bm;
  swz(blockIdx.x, bn, bm);
  f32x4 acc[4][4];
  const unsigned short* A1 = nxt_in + (size_t)bm * 128 * 1024;        // h0_t
  const unsigned short* A2 = cur + (size_t)bm * 128 * 1024 + 512;     // h1_{t-1}
  const unsigned short* B1 = Wc1p + (size_t)bn * 128 * 1024;
  gemm_core<16, 8>(A1, 1024, A2, 1024, B1, 1024, B1 + 512, 1024, lds, acc, tid);
  int lane = tid & 63, wid = tid >> 6, wm = wid & 1, wn = wid >> 1;
  int c16 = lane & 15, q = lane >> 4;
  int cg = bn * 32 + wn * 16 + c16;
  f32x4 bv = *(const f32x4*)&b1p4[cg * 4];
#pragma unroll
  for (int mf = 0; mf < 4; ++mf) {
    int row0 = bm * 128 + wm * 64 + mf * 16 + q * 4;
    f32x4 cold = *(const f32x4*)&c1[(size_t)cg * NROWS + row0];
    f32x4 cnew;
#pragma unroll
    for (int r = 0; r < 4; ++r) {
      size_t row = row0 + r;
      float gi = acc[mf][0][r] + bv.x;
      float gf = acc[mf][1][r] + bv.y;
      float gg = acc[mf][2][r] + bv.z;
      float go = acc[mf][3][r] + bv.w;
      float cn = fast_sigmoid(gf) * cold[r] + fast_sigmoid(gi) * fast_tanh(gg);
      cnew[r] = cn;
      nxt_out[row * 1024 + 512 + cg] = f2bf(fast_sigmoid(go) * fast_tanh(cn));
    }
    *(f32x4*)&c1[(size_t)cg * NROWS + row0] = cnew;
  }
}

// S3: pos = relu(h1 @ Wfc1^T + bfc1) @ Wfc2^T + bfc2 ; write preds[:,t], posb.
// R8: 704 blocks x 32 rows x 256 cols; 4 waves, wave w = 32 rows x 64 cols.
__global__ __launch_bounds__(256) void k_s3(const unsigned short* __restrict__ H,
                                            const unsigned short* __restrict__ Wfc1b,
                                            const float* __restrict__ bfc1,
                                            const float* __restrict__ Wfc2,
                                            const float* __restrict__ bfc2,
                                            float* __restrict__ out, float* __restrict__ posb,
                                            int t) {
  __shared__ __align__(16) unsigned short ldsA[32 * 64];    // 4 KB
  __shared__ __align__(16) unsigned short ldsB[256 * 64];   // 32 KB
  __shared__ float wfc2s[512];
  __shared__ float red[32 * 8];                             // [row][wave*2+d]
  int tid = threadIdx.x;
  // XCD-swizzle: s3 block covering rows [b32*32,+32) shares XCD with parent s2 bm=b32>>2
  int l = blockIdx.x, xcd = l & 7, i = l >> 3;              // i in 0..87
  int b32 = 4 * (xcd + 8 * (i >> 2)) + (i & 3);             // 0..703
  wfc2s[tid] = Wfc2[tid];
  wfc2s[tid + 256] = Wfc2[tid + 256];
  int lane = tid & 63, wid = tid >> 6;                      // wid = wave col-group
  int c16 = lane & 15, q = lane >> 4;
  f32x4 acc[2][4];
#pragma unroll
  for (int ii = 0; ii < 2; ++ii)
#pragma unroll
    for (int jj = 0; jj < 4; ++jj) acc[ii][jj] = f32x4{0.f, 0.f, 0.f, 0.f};
  const unsigned short* Ab = H + (size_t)b32 * 32 * 1024 + 512;
#pragma unroll
  for (int kt = 0; kt < 8; ++kt) {
    int k0 = kt * 64;
    __syncthreads();
    {
      int p = tid;                                          // 256 slots: 32 rows x 8 chunks
      int row = p >> 3, u = p & 7, ch = u ^ (row & 7);
      async_copy16(Ab + row * 1024 + k0 + ch * 8, ldsA + p * 8);
    }
#pragma unroll
    for (int rd = 0; rd < 8; ++rd) {
      int p = rd * 256 + tid;
      int row = p >> 3, u = p & 7, ch = u ^ (row & 7);
      async_copy16(Wfc1b + row * 512 + k0 + ch * 8, ldsB + p * 8);
    }
    __syncthreads();
#pragma unroll
    for (int s = 0; s < 2; ++s) {
      bf16x8 a[2], b[4];
#pragma unroll
      for (int mf = 0; mf < 2; ++mf) {
        int row = mf * 16 + c16;
        int slot = row * 8 + ((s * 4 + q) ^ (row & 7));
        a[mf] = *(const bf16x8*)(ldsA + slot * 8);
      }
#pragma unroll
      for (int nf = 0; nf < 4; ++nf) {
        int row = wid * 64 + nf * 16 + c16;
        int slot = row * 8 + ((s * 4 + q) ^ (row & 7));
        b[nf] = *(const bf16x8*)(ldsB + slot * 8);
      }
#pragma unroll
      for (int mf = 0; mf < 2; ++mf)
#pragma unroll
        for (int nf = 0; nf < 4; ++nf)
          acc[mf][nf] = __builtin_amdgcn_mfma_f32_16x16x32_bf16(a[mf], b[nf], acc[mf][nf], 0, 0, 0);
    }
  }
  float part[2][2][4];   // [d][mf][r]
#pragma unroll
  for (int d = 0; d < 2; ++d)
#pragma unroll
    for (int mf = 0; mf < 2; ++mf)
#pragma unroll
      for (int r = 0; r < 4; ++r) part[d][mf][r] = 0.f;
#pragma unroll
  for (int nf = 0; nf < 4; ++nf) {
    int col = wid * 64 + nf * 16 + c16;
    float w0 = wfc2s[col], w1 = wfc2s[256 + col], bv = bfc1[col];
#pragma unroll
    for (int mf = 0; mf < 2; ++mf)
#pragma unroll
      for (int r = 0; r < 4; ++r) {
        float v = acc[mf][nf][r] + bv;
        v = v > 0.f ? v : 0.f;
        part[0][mf][r] += v * w0;
        part[1][mf][r] += v * w1;
      }
  }
#pragma unroll
  for (int st = 1; st < 16; st <<= 1)
#pragma unroll
    for (int d = 0; d < 2; ++d)
#pragma unroll
      for (int mf = 0; mf < 2; ++mf)
#pragma unroll
        for (int r = 0; r < 4; ++r)
          part[d][mf][r] += __shfl_xor(part[d][mf][r], st, 64);
  if (c16 == 0) {
#pragma unroll
    for (int mf = 0; mf < 2; ++mf)
#pragma unroll
      for (int r = 0; r < 4; ++r) {
        int rl = mf * 16 + q * 4 + r;                      // 0..31
        red[rl * 8 + wid * 2 + 0] = part[0][mf][r];
        red[rl * 8 + wid * 2 + 1] = part[1][mf][r];
      }
  }
  __syncthreads();
  if (tid < 64) {
    int rl = tid >> 1, d = tid & 1;
    float s = red[rl * 8 + d] + red[rl * 8 + 2 + d] + red[rl * 8 + 4 + d]
            + red[rl * 8 + 6 + d] + bfc2[d];
    int rg = b32 * 32 + rl;
    out[((size_t)rg * T_STEPS + t) * 2 + d] = s;
    posb[rg * 2 + d] = s;
  }
}

// ---------------- launch ----------------
extern "C" void kernel_launch(void* const* d_in, const int* in_sizes, int n_in,
                              void* d_out, int out_size, void* d_ws, size_t ws_size,
                              hipStream_t stream) {
  (void)in_sizes; (void)n_in; (void)out_size;
  const float* ctx   = (const float*)d_in[0];
  const float* pos0  = (const float*)d_in[1];
  const float* ball  = (const float*)d_in[2];
  const int*   roles = (const int*)d_in[3];
  const float* role_table = (const float*)d_in[5];
  const float* Wih0 = (const float*)d_in[6];
  const float* Whh0 = (const float*)d_in[7];
  const float* b0   = (const float*)d_in[8];
  const float* Wih1 = (const float*)d_in[9];
  const float* Whh1 = (const float*)d_in[10];
  const float* b1   = (const float*)d_in[11];
  const float* Wfc1 = (const float*)d_in[12];
  const float* bfc1 = (const float*)d_in[13];
  const float* Wfc2 = (const float*)d_in[14];
  const float* bfc2 = (const float*)d_in[15];
  const float* Winit = (const float*)d_in[16];
  const float* binit = (const float*)d_in[17];
  float* out = (float*)d_out;

  char* w = (char*)d_ws;
  size_t used = 0;
  auto alloc = [&](size_t bytes) {
    char* p = w + used;
    used += (bytes + 255) & ~(size_t)255;
    return p;
  };
  unsigned short* W0p   = (unsigned short*)alloc((size_t)2048 * 512 * 2);
  unsigned short* Wc1p  = (unsigned short*)alloc((size_t)2048 * 1024 * 2);
  unsigned short* Wfc1b = (unsigned short*)alloc((size_t)256 * 512 * 2);
  float* Wposx = (float*)alloc(2048 * 4);
  float* Wposy = (float*)alloc(2048 * 4);
  float* b0p4  = (float*)alloc(2048 * 4);
  float* b1p4  = (float*)alloc(2048 * 4);
  float* posb  = (float*)alloc((size_t)NROWS * 2 * 4);
  unsigned short* Hc0 = (unsigned short*)alloc((size_t)NROWS * 1024 * 2);
  float* c0   = (float*)alloc((size_t)NROWS * 512 * 4);
  float* c1   = (float*)alloc((size_t)NROWS * 512 * 4);
  unsigned short* Hc1 = (unsigned short*)alloc((size_t)NROWS * 1024 * 2);

  const size_t SP_BYTES = (size_t)NROWS * 2048 * 2;           // 92.3 MB
  const bool use_sp = (ws_size >= used + SP_BYTES + (1u << 20));

  unsigned short *Xs, *Wsp, *SP2;
  if (use_sp) {
    SP2 = (unsigned short*)alloc(SP_BYTES);
    Xs  = Hc1;                                 // transient: dead before Hc1 is written
    Wsp = Hc1 + (size_t)NROWS * 384;
  } else {
    SP2 = Hc1;                                 // never dereferenced on lite path
    Xs  = (unsigned short*)alloc((size_t)NROWS * 384 * 2);
    Wsp = (unsigned short*)alloc((size_t)2048 * 384 * 2);
  }

  k_prep_w<<<2048, 512, 0, stream>>>(Whh0, Wih1, Whh1, Wih0, Wfc1, b0, b1,
                                     W0p, Wc1p, Wsp, Wfc1b, Wposx, Wposy, b0p4, b1p4);
  k_init_xs<<<NROWS, 384, 0, stream>>>(ball, ctx, roles, role_table, Xs);
  k_init_state<<<(NROWS * 512 + 255) / 256, 256, 0, stream>>>(pos0, Winit, binit, Hc0, c0, c1, posb);

  if (use_sp) {
    dim3 gs(16, NBM);
    k_static<<<gs, 256, 0, stream>>>(Xs, Wsp, b0p4, SP2);
  }

  for (int t = 0; t < T_STEPS; ++t) {
    unsigned short* cur = (t & 1) ? Hc1 : Hc0;
    unsigned short* nxt = (t & 1) ? Hc0 : Hc1;
    if (use_sp)
      k_s1<true><<<16 * NBM, 256, 0, stream>>>(cur, Xs, W0p, Wsp, SP2, b0p4, Wposx, Wposy, posb, c0, nxt);
    else
      k_s1<false><<<16 * NBM, 256, 0, stream>>>(cur, Xs, W0p, Wsp, SP2, b0p4, Wposx, Wposy, posb, c0, nxt);
    k_s2<<<16 * NBM, 256, 0, stream>>>(nxt, cur, Wc1p, b1p4, c1, nxt);
    k_s3<<<704, 256, 0, stream>>>(nxt, Wfc1b, bfc1, Wfc2, bfc2, out, posb, t);
  }
}